// Round 8
// baseline (223.990 us; speedup 1.0000x reference)
//
#include <hip/hip_runtime.h>
#include <hip/hip_bf16.h>
#include <stdint.h>

// ---------------------------------------------------------------------------
// CrossAttention B=4 N=512 M=2048 C=1024 H=16 D=64, bf16 MFMA fp32 accum.
// R8: (1) Q projection tiles paired like K+V -- all 576 gemm_qkv blocks are
// uniform dual-GEMMs (A-tile staged once per two weight tiles). (2) attention
// software-pipelined: S(qg+1) issues between softmax(qg) and PV(qg) so MFMA
// covers the ~120cy p_lds ds_read latency; sfr double-buffered (+16 VGPR,
// audit ~233 < 256 cap).
// ---------------------------------------------------------------------------

typedef __attribute__((ext_vector_type(4))) float f32x4;
typedef __attribute__((ext_vector_type(8))) __bf16 bf16x8;
typedef __attribute__((ext_vector_type(8))) unsigned short u16x8;

#define DEVI __device__ __forceinline__

// SCALE * log2(e): folded into Wq cast so QK^T scores land in log2 units.
#define QSC (0.125f * 1.44269504088896f)

DEVI f32x4 mfma16(u16x8 a, u16x8 b, f32x4 c) {
  return __builtin_amdgcn_mfma_f32_16x16x32_bf16(
      __builtin_bit_cast(bf16x8, a), __builtin_bit_cast(bf16x8, b), c, 0, 0, 0);
}

// round-to-nearest-even fp32 -> bf16
DEVI unsigned short f2bf(float f) {
  union { float f; unsigned int u; } x; x.f = f;
  unsigned int u = x.u;
  return (unsigned short)((u + 0x7fffu + ((u >> 16) & 1u)) >> 16);
}

DEVI float exp2_fast(float x) {
#if __has_builtin(__builtin_amdgcn_exp2f)
  return __builtin_amdgcn_exp2f(x);
#else
  return exp2f(x);
#endif
}

// async global->LDS, 16 bytes per lane (global_load_lds_dwordx4)
DEVI void llds16(const void* g, void* l) {
  __builtin_amdgcn_global_load_lds(
      (const __attribute__((address_space(1))) void*)g,
      (__attribute__((address_space(3))) void*)l, 16, 0, 0);
}

// ---------------------------------------------------------------------------
// One kernel casts all six fp32 inputs to bf16. Wq gets QSC folded in.
__global__ __launch_bounds__(256)
void cast_fused(const float* __restrict__ x, const float* __restrict__ ctx,
                const float* __restrict__ wq, const float* __restrict__ wk,
                const float* __restrict__ wv, const float* __restrict__ wo,
                unsigned short* __restrict__ xb, unsigned short* __restrict__ cb,
                unsigned short* __restrict__ wqb, unsigned short* __restrict__ wkb,
                unsigned short* __restrict__ wvb, unsigned short* __restrict__ wob) {
  int bid = blockIdx.x;
  const float* src; unsigned short* dst; float scale = 1.f;
  if (bid < 2048)        { src = x;   dst = xb; }
  else if (bid < 10240)  { src = ctx; dst = cb;  bid -= 2048; }
  else if (bid < 11264)  { src = wq;  dst = wqb; bid -= 10240; scale = QSC; }
  else if (bid < 12288)  { src = wk;  dst = wkb; bid -= 11264; }
  else if (bid < 13312)  { src = wv;  dst = wvb; bid -= 12288; }
  else                   { src = wo;  dst = wob; bid -= 13312; }
  int idx = (bid * 256 + threadIdx.x) * 4;
  const float4 v = *(const float4*)(src + idx);
  ushort4 o;
  o.x = f2bf(v.x * scale); o.y = f2bf(v.y * scale);
  o.z = f2bf(v.z * scale); o.w = f2bf(v.w * scale);
  *(ushort4*)(dst + idx) = o;
}

// ---------------------------------------------------------------------------
// Epilogue helper: stage a 128x128 bf16 C tile through LDS, store coalesced.
// mode 0: [B,H,S,64] permute (S = 1<<logS). mode 2: V^T [bh][d][2048].
DEVI void epi_store(f32x4 (&acc)[4][4], const float* __restrict__ bias,
                    float bscale, void* __restrict__ Cout,
                    int bm, int bn, int logS, int mode,
                    unsigned short* cst, int tid, int wave, int l15, int quad) {
  const int wm = wave & 1, wn = wave >> 1;
  __syncthreads();
  for (int half = 0; half < 2; ++half) {
    if (wm == half) {
#pragma unroll
      for (int mi = 0; mi < 4; ++mi)
#pragma unroll
        for (int ni = 0; ni < 4; ++ni)
#pragma unroll
          for (int r = 0; r < 4; ++r) {
            int lrow = mi * 16 + quad * 4 + r;          // 0..63
            int lcol = wn * 64 + ni * 16 + l15;         // 0..127
            unsigned short bv = f2bf(acc[mi][ni][r] + bias[bn + lcol] * bscale);
            if (mode == 0) cst[lrow * 136 + lcol] = bv;
            else           cst[lcol * 72 + lrow] = bv;  // transposed
          }
    }
    __syncthreads();
    if (mode == 0) {
      int lrow = tid >> 2, cc = (tid & 3) * 32;
      int row = bm + half * 64 + lrow;
      int b = row >> logS, sl = row & ((1 << logS) - 1);
#pragma unroll
      for (int j = 0; j < 4; ++j) {
        int col = bn + cc + j * 8;
        int h = col >> 6, d = col & 63;
        *(u16x8*)&((unsigned short*)Cout)[(((size_t)(b * 16 + h) << logS) + sl) * 64 + d] =
            *(const u16x8*)&cst[lrow * 136 + cc + j * 8];
      }
    } else {
      int c = tid >> 1, rc = (tid & 1) * 32;
      int gc = bn + c, h = gc >> 6, d = gc & 63;
      int b = bm >> 11;
      size_t base = ((size_t)(b * 16 + h) * 64 + d) * 2048 + (bm & 2047) + half * 64 + rc;
#pragma unroll
      for (int j = 0; j < 4; ++j)
        *(u16x8*)&((unsigned short*)Cout)[base + j * 8] =
            *(const u16x8*)&cst[c * 72 + rc + j * 8];
    }
    __syncthreads();
  }
}

// ---------------------------------------------------------------------------
// Dual-GEMM body: both GEMMs read the same A rows; stage A once per K-step,
// run W1 and W2 tiles against it. 64 MFMA per barrier pair.
DEVI void dual_body(const unsigned short* __restrict__ A,
                    const unsigned short* __restrict__ W1,
                    const unsigned short* __restrict__ W2,
                    const float* __restrict__ b1, const float* __restrict__ b2,
                    unsigned short* __restrict__ out1, unsigned short* __restrict__ out2,
                    int bm, int bn1, int bn2, int logS, float bscale, int mode2,
                    unsigned short* sh) {
  constexpr int K = 1024;
  unsigned short* As = sh;
  unsigned short* Ks = sh + 128 * 64;
  unsigned short* Vs = sh + 2 * 128 * 64;

  const int tid = threadIdx.x;
  const int wave = tid >> 6, lane = tid & 63;
  const int l15 = lane & 15, quad = lane >> 4;
  const int wm = wave & 1, wn = wave >> 1;

  f32x4 ak[4][4] = {}, av[4][4] = {};

  for (int k0 = 0; k0 < K; k0 += 64) {
    __syncthreads();
#pragma unroll
    for (int c = 0; c < 4; ++c) {
      int s = c * 256 + tid;
      int m = s >> 3;
      int k8 = (s & 7) ^ (m & 7);
      llds16(A + (size_t)(bm + m) * K + k0 + k8 * 8, &As[s * 8]);
      llds16(W1 + (size_t)(bn1 + m) * K + k0 + k8 * 8, &Ks[s * 8]);
      llds16(W2 + (size_t)(bn2 + m) * K + k0 + k8 * 8, &Vs[s * 8]);
    }
    __syncthreads();
#pragma unroll
    for (int ks = 0; ks < 2; ++ks) {
      const int k8 = ks * 4 + quad;
      u16x8 af[4], bf[4];
#pragma unroll
      for (int i = 0; i < 4; ++i) {
        int m = wm * 64 + i * 16 + l15;
        af[i] = *(const u16x8*)(&As[(m * 8 + (k8 ^ (m & 7))) * 8]);
      }
#pragma unroll
      for (int i = 0; i < 4; ++i) {
        int n = wn * 64 + i * 16 + l15;
        bf[i] = *(const u16x8*)(&Ks[(n * 8 + (k8 ^ (n & 7))) * 8]);
      }
#pragma unroll
      for (int mi = 0; mi < 4; ++mi)
#pragma unroll
        for (int ni = 0; ni < 4; ++ni)
          ak[mi][ni] = mfma16(af[mi], bf[ni], ak[mi][ni]);
#pragma unroll
      for (int i = 0; i < 4; ++i) {
        int n = wn * 64 + i * 16 + l15;
        bf[i] = *(const u16x8*)(&Vs[(n * 8 + (k8 ^ (n & 7))) * 8]);
      }
#pragma unroll
      for (int mi = 0; mi < 4; ++mi)
#pragma unroll
        for (int ni = 0; ni < 4; ++ni)
          av[mi][ni] = mfma16(af[mi], bf[ni], av[mi][ni]);
    }
  }

  epi_store(ak, b1, bscale, out1, bm, bn1, logS, 0, sh, tid, wave, l15, quad);
  epi_store(av, b2, bscale, out2, bm, bn2, logS, mode2, sh, tid, wave, l15, quad);
}

// Fused Q/K/V projection, uniform dual-GEMM blocks. Grid (64, 9).
// y in [0,8): K+V dual tiles; y == 8: Q dual tiles (two column tiles).
__global__ __launch_bounds__(256, 2)
void gemm_qkv(const unsigned short* __restrict__ xb,
              const unsigned short* __restrict__ cb,
              const unsigned short* __restrict__ wq,
              const unsigned short* __restrict__ wk,
              const unsigned short* __restrict__ wv,
              const float* __restrict__ bq, const float* __restrict__ bk,
              const float* __restrict__ bv,
              unsigned short* __restrict__ qh, unsigned short* __restrict__ kh,
              unsigned short* __restrict__ vt) {
  __shared__ __align__(16) unsigned short sh[128 * 64 * 3];  // 48 KB
  const int x = blockIdx.x, y = blockIdx.y;
  if (y < 8) {
    dual_body(cb, wk, wv, bk, bv, kh, vt, x * 128, y * 128, y * 128, 11, 1.f, 2, sh);
  } else {
    int bm = (x & 15) * 128, bn = (x >> 4) * 128;
    dual_body(xb, wq, wq, bq, bq, qh, qh, bm, bn, bn + 512, 9, QSC, 0, sh);
  }
}

// ---------------------------------------------------------------------------
// Output projection: out[2048,1024] fp32 = ah @ Wo^T + bo. 64x128 tile,
// grid (32, 8) = 256 blocks (one per CU), 4 waves each 64 rows x 32 cols.
__global__ __launch_bounds__(256)
void gemm_o(const unsigned short* __restrict__ A,
            const unsigned short* __restrict__ W,
            const float* __restrict__ bo, float* __restrict__ out) {
  constexpr int K = 1024;
  __shared__ __align__(16) unsigned short As[64 * 64];   // 8 KB
  __shared__ __align__(16) unsigned short Bs[128 * 64];  // 16 KB

  const int tid = threadIdx.x;
  const int wave = tid >> 6, lane = tid & 63;
  const int l15 = lane & 15, quad = lane >> 4;
  const int bm = blockIdx.x * 64, bn = blockIdx.y * 128;

  f32x4 acc[4][2] = {};

  for (int k0 = 0; k0 < K; k0 += 64) {
    __syncthreads();
#pragma unroll
    for (int c = 0; c < 2; ++c) {
      int s = c * 256 + tid;
      int m = s >> 3, k8 = (s & 7) ^ (m & 7);
      llds16(A + (size_t)(bm + m) * K + k0 + k8 * 8, &As[s * 8]);
    }
#pragma unroll
    for (int c = 0; c < 4; ++c) {
      int s = c * 256 + tid;
      int m = s >> 3, k8 = (s & 7) ^ (m & 7);
      llds16(W + (size_t)(bn + m) * K + k0 + k8 * 8, &Bs[s * 8]);
    }
    __syncthreads();
#pragma unroll
    for (int ks = 0; ks < 2; ++ks) {
      const int k8 = ks * 4 + quad;
      u16x8 af[4], bf[2];
#pragma unroll
      for (int i = 0; i < 4; ++i) {
        int m = i * 16 + l15;
        af[i] = *(const u16x8*)(&As[(m * 8 + (k8 ^ (m & 7))) * 8]);
      }
#pragma unroll
      for (int i = 0; i < 2; ++i) {
        int n = wave * 32 + i * 16 + l15;
        bf[i] = *(const u16x8*)(&Bs[(n * 8 + (k8 ^ (n & 7))) * 8]);
      }
#pragma unroll
      for (int mi = 0; mi < 4; ++mi)
#pragma unroll
        for (int ni = 0; ni < 2; ++ni)
          acc[mi][ni] = mfma16(af[mi], bf[ni], acc[mi][ni]);
    }
  }

#pragma unroll
  for (int mi = 0; mi < 4; ++mi)
#pragma unroll
    for (int ni = 0; ni < 2; ++ni)
#pragma unroll
      for (int r = 0; r < 4; ++r) {
        int row = bm + mi * 16 + quad * 4 + r;
        int col = bn + wave * 32 + ni * 16 + l15;
        out[(size_t)row * 1024 + col] = acc[mi][ni][r] + bo[col];
      }
}

// ---------------------------------------------------------------------------
// Split-K flash attention, fixed-max softmax, software-pipelined S/PV.
// Grid (64 bh, 8 qblk), block 256. Wave w covers keys {w*64 + 256t}; no
// barriers in the main loop. Pipeline: S(qg+1) issues between softmax(qg)
// and PV(qg) so its MFMAs cover PV's p_lds ds_read latency. kf reloads at
// qg==2 (right after its last use in S(3)). sfr double-buffered.
// PS: p_lds row stride in u16. MUST be == 0 mod 8 (16 B) -- P fragments are
// read as u16x8 (ds_read_b128); any other stride misaligns odd q-rows.
#define PS 72
__global__ __launch_bounds__(256, 2)
void attn_kernel(const unsigned short* __restrict__ Q,   // [64][512][64]
                 const unsigned short* __restrict__ K,   // [64][2048][64]
                 const unsigned short* __restrict__ Vt,  // [64][64][2048]
                 const int* __restrict__ mask,           // [4][2048]
                 unsigned short* __restrict__ O) {       // [4][512][1024]
  __shared__ float bias_lds[2048];
  __shared__ __align__(16) unsigned short p_lds[4][2][16 * PS];
  __shared__ float l_lds[4][64];
  __shared__ __align__(16) float o_comb[64][68];

  const int tid = threadIdx.x;
  const int wave = tid >> 6, lane = tid & 63;
  const int l15 = lane & 15, quad = lane >> 4;
  const int bh = blockIdx.x, b = bh >> 4, h = bh & 15;
  const int q0 = blockIdx.y * 64;

  {  // mask -> additive bias in log2 units, with fixed max-shift -8 folded in
    const int* mb = mask + b * 2048;
    for (int i = tid; i < 2048; i += 256)
      bias_lds[i] = mb[i] ? -8.f : -1e30f;
  }
  __syncthreads();

  const unsigned short* Qb = Q + ((size_t)bh * 512 + q0) * 64;
  const unsigned short* Kb = K + (size_t)bh * (2048 * 64);
  const unsigned short* Vb = Vt + (size_t)bh * (64 * 2048);

  // Q fragments: lane l15 = q row, elements = d. Held all kernel.
  u16x8 aq[4][2];
#pragma unroll
  for (int qg = 0; qg < 4; ++qg)
#pragma unroll
    for (int ks = 0; ks < 2; ++ks)
      aq[qg][ks] = *(const u16x8*)(Qb + (qg * 16 + l15) * 64 + ks * 32 + quad * 8);

  f32x4 o_acc[4][4] = {};
  float l_s[4] = {0.f, 0.f, 0.f, 0.f};

  u16x8 kf[2][4];

  auto load_k = [&](int kb) {
#pragma unroll
    for (int ns = 0; ns < 4; ++ns)
#pragma unroll
      for (int ks = 0; ks < 2; ++ks)
        kf[ks][ns] = *(const u16x8*)(Kb + (size_t)(kb + ns * 16 + l15) * 64 + ks * 32 + quad * 8);
  };

  load_k(wave * 64);

#pragma unroll 1
  for (int t = 0; t < 8; ++t) {
    const int kb = wave * 64 + t * 256;
    const int kb_next = kb + (t < 7 ? 256 : 0);

    // V^T frags (B-op: lane=d, elems=key): consumed in PV; first use is far
    // from issue (S + softmax of qg0 in between).
    u16x8 vf[2][4];
#pragma unroll
    for (int nd = 0; nd < 4; ++nd)
#pragma unroll
      for (int ks = 0; ks < 2; ++ks)
        vf[ks][nd] = *(const u16x8*)(Vb + (size_t)(nd * 16 + l15) * 2048 + kb + ks * 32 + quad * 8);
    f32x4 bfr[4];
#pragma unroll
    for (int ns = 0; ns < 4; ++ns)
      bfr[ns] = *(const f32x4*)&bias_lds[kb + ns * 16 + quad * 4];

    // S^T tile for qg: D[key = ns*16+quad*4+r][q = l15], C-init = bias.
    f32x4 sfr[2][4];
    auto do_S = [&](int buf, int qg) {
#pragma unroll
      for (int ns = 0; ns < 4; ++ns) {
        f32x4 sa = bfr[ns];
#pragma unroll
        for (int ks = 0; ks < 2; ++ks)
          sa = mfma16(kf[ks][ns], aq[qg][ks], sa);
        sfr[buf][ns] = sa;
      }
    };

    do_S(0, 0);
#pragma unroll
    for (int qg = 0; qg < 4; ++qg) {
      const int buf = qg & 1;
      // softmax(qg): exp2, pack to bf16, stash in p_lds, accumulate l
      float rsum = 0.f;
#pragma unroll
      for (int ns = 0; ns < 4; ++ns) {
        unsigned int pr[4];
#pragma unroll
        for (int r = 0; r < 4; ++r) {
          float p = exp2_fast(sfr[buf][ns][r]);
          unsigned int u = __builtin_bit_cast(unsigned int, p) & 0xffff0000u;
          rsum += __builtin_bit_cast(float, u);  // sum TRUNCATED p: consistent with PV
          pr[r] = u;
        }
        uint2 pw;
        pw.x = __builtin_amdgcn_perm(pr[1], pr[0], 0x07060302u);
        pw.y = __builtin_amdgcn_perm(pr[3], pr[2], 0x07060302u);
        *(uint2*)&p_lds[wave][buf][l15 * PS + ns * 16 + quad * 4] = pw;
      }
      rsum += __shfl_xor(rsum, 16, 64);
      rsum += __shfl_xor(rsum, 32, 64);
      l_s[qg] += rsum;

      // issue S(qg+1) now: its MFMAs cover PV(qg)'s ds_read latency
      if (qg < 3) do_S(buf ^ 1, qg + 1);
      // kf dead after S(3) (issued in qg==2 iteration): reload for next tile
      if (qg == 2) load_k(kb_next);

      // PV(qg): A = P (lane=q, elems=key) from p_lds; B = V^T frags
#pragma unroll
      for (int ks = 0; ks < 2; ++ks) {
        u16x8 pf = *(const u16x8*)&p_lds[wave][buf][l15 * PS + ks * 32 + quad * 8];
#pragma unroll
        for (int nd = 0; nd < 4; ++nd)
          o_acc[qg][nd] = mfma16(pf, vf[ks][nd], o_acc[qg][nd]);
      }
    }
  }

  // ---- combine the 4 waves' partial (l, o): plain sums (fixed max) ----
  if (quad == 0) {
#pragma unroll
    for (int qg = 0; qg < 4; ++qg)
      l_lds[wave][qg * 16 + l15] = l_s[qg];
  }
  __syncthreads();

  for (int w = 0; w < 4; ++w) {
    if (wave == w) {
#pragma unroll
      for (int qg = 0; qg < 4; ++qg)
#pragma unroll
        for (int r = 0; r < 4; ++r) {
          const int q = qg * 16 + quad * 4 + r;
#pragma unroll
          for (int nd = 0; nd < 4; ++nd) {
            const int d = nd * 16 + l15;
            float v = o_acc[qg][nd][r];
            if (w == 0) o_comb[q][d] = v;
            else        o_comb[q][d] += v;
          }
        }
    }
    __syncthreads();
  }

  // ---- final normalize + store (two u16x8 per thread) ----
  {
    const int q = tid >> 2, dc = (tid & 3) * 16;
    const float inv = 1.f / (l_lds[0][q] + l_lds[1][q] + l_lds[2][q] + l_lds[3][q]);
    unsigned short* Ob = O + ((size_t)(b * 512 + q0 + q)) * 1024 + h * 64 + dc;
    u16x8 o1, o2;
#pragma unroll
    for (int j = 0; j < 8; ++j) o1[j] = f2bf(o_comb[q][dc + j] * inv);
#pragma unroll
    for (int j = 0; j < 8; ++j) o2[j] = f2bf(o_comb[q][dc + 8 + j] * inv);
    *(u16x8*)(Ob) = o1;
    *(u16x8*)(Ob + 8) = o2;
  }
}

// ---------------------------------------------------------------------------
extern "C" void kernel_launch(void* const* d_in, const int* in_sizes, int n_in,
                              void* d_out, int out_size, void* d_ws, size_t ws_size,
                              hipStream_t stream) {
  const float* x   = (const float*)d_in[0];
  const float* ctx = (const float*)d_in[1];
  const int* mask  = (const int*)d_in[2];
  const float* Wq  = (const float*)d_in[3];
  const float* bq  = (const float*)d_in[4];
  const float* Wk  = (const float*)d_in[5];
  const float* bk  = (const float*)d_in[6];
  const float* Wv  = (const float*)d_in[7];
  const float* bv  = (const float*)d_in[8];
  const float* Wo  = (const float*)d_in[9];
  const float* bo  = (const float*)d_in[10];

  char* ws = (char*)d_ws;
  // [MB] xb 0-4, cb 4-20, w 20-28, qh 28-32, kh 32-48, vt 48-64, ah 64-68.
  unsigned short* xb  = (unsigned short*)(ws + ((size_t)0  << 20));
  unsigned short* cb  = (unsigned short*)(ws + ((size_t)4  << 20));
  unsigned short* wqb = (unsigned short*)(ws + ((size_t)20 << 20));
  unsigned short* wkb = (unsigned short*)(ws + ((size_t)22 << 20));
  unsigned short* wvb = (unsigned short*)(ws + ((size_t)24 << 20));
  unsigned short* wob = (unsigned short*)(ws + ((size_t)26 << 20));
  unsigned short* qh  = (unsigned short*)(ws + ((size_t)28 << 20));
  unsigned short* kh  = (unsigned short*)(ws + ((size_t)32 << 20));
  unsigned short* vt  = (unsigned short*)(ws + ((size_t)48 << 20));
  unsigned short* ah  = (unsigned short*)(ws + ((size_t)64 << 20));

  cast_fused<<<14336, 256, 0, stream>>>(x, ctx, Wq, Wk, Wv, Wo,
                                        xb, cb, wqb, wkb, wvb, wob);
  gemm_qkv<<<dim3(64, 9), 256, 0, stream>>>(xb, cb, wqb, wkb, wvb,
                                            bq, bk, bv, qh, kh, vt);
  attn_kernel<<<dim3(64, 8), 256, 0, stream>>>(qh, kh, vt, mask, ah);
  gemm_o<<<dim3(32, 8), 256, 0, stream>>>(ah, wob, bo, (float*)d_out);
}

// Round 9
// 212.000 us; speedup vs baseline: 1.0566x; 1.0566x over previous
//
#include <hip/hip_runtime.h>
#include <hip/hip_bf16.h>
#include <stdint.h>

// ---------------------------------------------------------------------------
// CrossAttention B=4 N=512 M=2048 C=1024 H=16 D=64, bf16 MFMA fp32 accum.
// R9: revert R8's uniform-dual qkv grid (tail of full-length blocks was
// worse; short Q blocks go last again) and R8's neutral S/PV pipelining.
// NEW: Q/K/V stored in MFMA-fragment-major layout [bh][grp][chunk][l16][8]
// so every attn fragment load is one contiguous 1KB wave-load instead of a
// 16-cache-line gather (16x fewer line transactions through TA/L2).
// attn gets launch_bounds(256,1) to rule out hidden spills.
// ---------------------------------------------------------------------------

typedef __attribute__((ext_vector_type(4))) float f32x4;
typedef __attribute__((ext_vector_type(8))) __bf16 bf16x8;
typedef __attribute__((ext_vector_type(8))) unsigned short u16x8;

#define DEVI __device__ __forceinline__

// SCALE * log2(e): folded into Wq cast so QK^T scores land in log2 units.
#define QSC (0.125f * 1.44269504088896f)

DEVI f32x4 mfma16(u16x8 a, u16x8 b, f32x4 c) {
  return __builtin_amdgcn_mfma_f32_16x16x32_bf16(
      __builtin_bit_cast(bf16x8, a), __builtin_bit_cast(bf16x8, b), c, 0, 0, 0);
}

// round-to-nearest-even fp32 -> bf16
DEVI unsigned short f2bf(float f) {
  union { float f; unsigned int u; } x; x.f = f;
  unsigned int u = x.u;
  return (unsigned short)((u + 0x7fffu + ((u >> 16) & 1u)) >> 16);
}

DEVI float exp2_fast(float x) {
#if __has_builtin(__builtin_amdgcn_exp2f)
  return __builtin_amdgcn_exp2f(x);
#else
  return exp2f(x);
#endif
}

// async global->LDS, 16 bytes per lane (global_load_lds_dwordx4)
DEVI void llds16(const void* g, void* l) {
  __builtin_amdgcn_global_load_lds(
      (const __attribute__((address_space(1))) void*)g,
      (__attribute__((address_space(3))) void*)l, 16, 0, 0);
}

// ---------------------------------------------------------------------------
// One kernel casts all six fp32 inputs to bf16. Wq gets QSC folded in.
__global__ __launch_bounds__(256)
void cast_fused(const float* __restrict__ x, const float* __restrict__ ctx,
                const float* __restrict__ wq, const float* __restrict__ wk,
                const float* __restrict__ wv, const float* __restrict__ wo,
                unsigned short* __restrict__ xb, unsigned short* __restrict__ cb,
                unsigned short* __restrict__ wqb, unsigned short* __restrict__ wkb,
                unsigned short* __restrict__ wvb, unsigned short* __restrict__ wob) {
  int bid = blockIdx.x;
  const float* src; unsigned short* dst; float scale = 1.f;
  if (bid < 2048)        { src = x;   dst = xb; }
  else if (bid < 10240)  { src = ctx; dst = cb;  bid -= 2048; }
  else if (bid < 11264)  { src = wq;  dst = wqb; bid -= 10240; scale = QSC; }
  else if (bid < 12288)  { src = wk;  dst = wkb; bid -= 11264; }
  else if (bid < 13312)  { src = wv;  dst = wvb; bid -= 12288; }
  else                   { src = wo;  dst = wob; bid -= 13312; }
  int idx = (bid * 256 + threadIdx.x) * 4;
  const float4 v = *(const float4*)(src + idx);
  ushort4 o;
  o.x = f2bf(v.x * scale); o.y = f2bf(v.y * scale);
  o.z = f2bf(v.z * scale); o.w = f2bf(v.w * scale);
  *(ushort4*)(dst + idx) = o;
}

// ---------------------------------------------------------------------------
// Epilogue helper: stage a 128x128 bf16 C tile through LDS, store coalesced.
// mode 0: fragment-major [bh][grp=idx/16][d8][idx&15][8] (bh-extent S=1<<logS).
// mode 2: V^T fragment-major [bh][key/64][d/16][key8][d&15][8].
DEVI void epi_store(f32x4 (&acc)[4][4], const float* __restrict__ bias,
                    float bscale, void* __restrict__ Cout,
                    int bm, int bn, int logS, int mode,
                    unsigned short* cst, int tid, int wave, int l15, int quad) {
  const int wm = wave & 1, wn = wave >> 1;
  __syncthreads();
  for (int half = 0; half < 2; ++half) {
    if (wm == half) {
#pragma unroll
      for (int mi = 0; mi < 4; ++mi)
#pragma unroll
        for (int ni = 0; ni < 4; ++ni)
#pragma unroll
          for (int r = 0; r < 4; ++r) {
            int lrow = mi * 16 + quad * 4 + r;          // 0..63
            int lcol = wn * 64 + ni * 16 + l15;         // 0..127
            unsigned short bv = f2bf(acc[mi][ni][r] + bias[bn + lcol] * bscale);
            if (mode == 0) cst[lrow * 136 + lcol] = bv;
            else           cst[lcol * 72 + lrow] = bv;  // transposed
          }
    }
    __syncthreads();
    if (mode == 0) {
      // fragment-major: one u16x8 = (idx fixed, 8 consecutive d)
      int lrow = tid >> 2, cc = (tid & 3) * 32;
      int row = bm + half * 64 + lrow;
      int S = 1 << logS;
      int b = row >> logS, sl = row & (S - 1);
#pragma unroll
      for (int j = 0; j < 4; ++j) {
        int col = bn + cc + j * 8;
        int h = col >> 6, d8 = (col & 63) >> 3;
        size_t base = (((size_t)(b * 16 + h)) << logS) * 64 +
                      (size_t)(sl >> 4) * 1024 + d8 * 128 + (sl & 15) * 8;
        *(u16x8*)&((unsigned short*)Cout)[base] =
            *(const u16x8*)&cst[lrow * 136 + cc + j * 8];
      }
    } else {
      // V^T fragment-major: one u16x8 = (d fixed, 8 consecutive keys)
      int c = tid >> 1, rc = (tid & 1) * 32;
      int gc = bn + c, h = gc >> 6, d = gc & 63;
      int b = bm >> 11;
#pragma unroll
      for (int j = 0; j < 4; ++j) {
        int key = (bm & 2047) + half * 64 + rc + j * 8;
        size_t base = (size_t)(b * 16 + h) * 131072 +
                      (size_t)(((key >> 6) * 4 + (d >> 4)) * 8 + ((key >> 3) & 7)) * 128 +
                      (d & 15) * 8;
        *(u16x8*)&((unsigned short*)Cout)[base] =
            *(const u16x8*)&cst[c * 72 + rc + j * 8];
      }
    }
    __syncthreads();
  }
}

// ---------------------------------------------------------------------------
// Fused K+V body: both GEMMs read the same A rows; stage A once per K-step,
// run Wk and Wv tiles against it. 64 MFMA per barrier pair.
DEVI void kv_body(const unsigned short* __restrict__ A,
                  const unsigned short* __restrict__ WK,
                  const unsigned short* __restrict__ WV,
                  const float* __restrict__ bk, const float* __restrict__ bv,
                  unsigned short* __restrict__ kh, unsigned short* __restrict__ vt,
                  int bm, int bn, unsigned short* sh) {
  constexpr int K = 1024;
  unsigned short* As = sh;
  unsigned short* Ks = sh + 128 * 64;
  unsigned short* Vs = sh + 2 * 128 * 64;

  const int tid = threadIdx.x;
  const int wave = tid >> 6, lane = tid & 63;
  const int l15 = lane & 15, quad = lane >> 4;
  const int wm = wave & 1, wn = wave >> 1;

  f32x4 ak[4][4] = {}, av[4][4] = {};

  for (int k0 = 0; k0 < K; k0 += 64) {
    __syncthreads();
#pragma unroll
    for (int c = 0; c < 4; ++c) {
      int s = c * 256 + tid;
      int m = s >> 3;
      int k8 = (s & 7) ^ (m & 7);
      llds16(A + (size_t)(bm + m) * K + k0 + k8 * 8, &As[s * 8]);
      llds16(WK + (size_t)(bn + m) * K + k0 + k8 * 8, &Ks[s * 8]);
      llds16(WV + (size_t)(bn + m) * K + k0 + k8 * 8, &Vs[s * 8]);
    }
    __syncthreads();
#pragma unroll
    for (int ks = 0; ks < 2; ++ks) {
      const int k8 = ks * 4 + quad;
      u16x8 af[4], bf[4];
#pragma unroll
      for (int i = 0; i < 4; ++i) {
        int m = wm * 64 + i * 16 + l15;
        af[i] = *(const u16x8*)(&As[(m * 8 + (k8 ^ (m & 7))) * 8]);
      }
#pragma unroll
      for (int i = 0; i < 4; ++i) {
        int n = wn * 64 + i * 16 + l15;
        bf[i] = *(const u16x8*)(&Ks[(n * 8 + (k8 ^ (n & 7))) * 8]);
      }
#pragma unroll
      for (int mi = 0; mi < 4; ++mi)
#pragma unroll
        for (int ni = 0; ni < 4; ++ni)
          ak[mi][ni] = mfma16(af[mi], bf[ni], ak[mi][ni]);
#pragma unroll
      for (int i = 0; i < 4; ++i) {
        int n = wn * 64 + i * 16 + l15;
        bf[i] = *(const u16x8*)(&Vs[(n * 8 + (k8 ^ (n & 7))) * 8]);
      }
#pragma unroll
      for (int mi = 0; mi < 4; ++mi)
#pragma unroll
        for (int ni = 0; ni < 4; ++ni)
          av[mi][ni] = mfma16(af[mi], bf[ni], av[mi][ni]);
    }
  }

  epi_store(ak, bk, 1.f, kh, bm, bn, 11, 0, sh, tid, wave, l15, quad);
  epi_store(av, bv, 1.f, vt, bm, bn, 11, 2, sh, tid, wave, l15, quad);
}

// Single-GEMM body (Q projection), mode 0 epilogue.
DEVI void q_body(const unsigned short* __restrict__ A,
                 const unsigned short* __restrict__ W,
                 const float* __restrict__ bias,
                 unsigned short* __restrict__ Cout,
                 int bm, int bn, unsigned short* sh) {
  constexpr int K = 1024;
  unsigned short* As = sh;
  unsigned short* Bs = sh + 128 * 64;

  const int tid = threadIdx.x;
  const int wave = tid >> 6, lane = tid & 63;
  const int l15 = lane & 15, quad = lane >> 4;
  const int wm = wave & 1, wn = wave >> 1;

  f32x4 acc[4][4] = {};

  for (int k0 = 0; k0 < K; k0 += 64) {
    __syncthreads();
#pragma unroll
    for (int c = 0; c < 4; ++c) {
      int s = c * 256 + tid;
      int m = s >> 3;
      int k8 = (s & 7) ^ (m & 7);
      llds16(A + (size_t)(bm + m) * K + k0 + k8 * 8, &As[s * 8]);
      llds16(W + (size_t)(bn + m) * K + k0 + k8 * 8, &Bs[s * 8]);
    }
    __syncthreads();
#pragma unroll
    for (int ks = 0; ks < 2; ++ks) {
      const int k8 = ks * 4 + quad;
      u16x8 af[4], bf[4];
#pragma unroll
      for (int i = 0; i < 4; ++i) {
        int m = wm * 64 + i * 16 + l15;
        af[i] = *(const u16x8*)(&As[(m * 8 + (k8 ^ (m & 7))) * 8]);
        int n = wn * 64 + i * 16 + l15;
        bf[i] = *(const u16x8*)(&Bs[(n * 8 + (k8 ^ (n & 7))) * 8]);
      }
#pragma unroll
      for (int mi = 0; mi < 4; ++mi)
#pragma unroll
        for (int ni = 0; ni < 4; ++ni)
          acc[mi][ni] = mfma16(af[mi], bf[ni], acc[mi][ni]);
    }
  }

  epi_store(acc, bias, QSC, Cout, bm, bn, 9, 0, sh, tid, wave, l15, quad);
}

// Fused Q/K/V projection. Grid (64, 10): y<8 K+V duals, y in {8,9} Q singles
// (short blocks dispatched LAST -> short tail; R8's uniform grid regressed).
__global__ __launch_bounds__(256, 2)
void gemm_qkv(const unsigned short* __restrict__ xb,
              const unsigned short* __restrict__ cb,
              const unsigned short* __restrict__ wq,
              const unsigned short* __restrict__ wk,
              const unsigned short* __restrict__ wv,
              const float* __restrict__ bq, const float* __restrict__ bk,
              const float* __restrict__ bv,
              unsigned short* __restrict__ qh, unsigned short* __restrict__ kh,
              unsigned short* __restrict__ vt) {
  __shared__ __align__(16) unsigned short sh[128 * 64 * 3];  // 48 KB
  const int x = blockIdx.x, y = blockIdx.y;
  if (y < 8) {
    kv_body(cb, wk, wv, bk, bv, kh, vt, x * 128, y * 128, sh);
  } else {
    q_body(xb, wq, bq, qh, (x & 15) * 128, (y - 8) * 512 + (x >> 4) * 128, sh);
  }
}

// ---------------------------------------------------------------------------
// Output projection: out[2048,1024] fp32 = ah @ Wo^T + bo. 64x128 tile,
// grid (32, 8) = 256 blocks (one per CU), 4 waves each 64 rows x 32 cols.
__global__ __launch_bounds__(256)
void gemm_o(const unsigned short* __restrict__ A,
            const unsigned short* __restrict__ W,
            const float* __restrict__ bo, float* __restrict__ out) {
  constexpr int K = 1024;
  __shared__ __align__(16) unsigned short As[64 * 64];   // 8 KB
  __shared__ __align__(16) unsigned short Bs[128 * 64];  // 16 KB

  const int tid = threadIdx.x;
  const int wave = tid >> 6, lane = tid & 63;
  const int l15 = lane & 15, quad = lane >> 4;
  const int bm = blockIdx.x * 64, bn = blockIdx.y * 128;

  f32x4 acc[4][2] = {};

  for (int k0 = 0; k0 < K; k0 += 64) {
    __syncthreads();
#pragma unroll
    for (int c = 0; c < 2; ++c) {
      int s = c * 256 + tid;
      int m = s >> 3, k8 = (s & 7) ^ (m & 7);
      llds16(A + (size_t)(bm + m) * K + k0 + k8 * 8, &As[s * 8]);
    }
#pragma unroll
    for (int c = 0; c < 4; ++c) {
      int s = c * 256 + tid;
      int m = s >> 3, k8 = (s & 7) ^ (m & 7);
      llds16(W + (size_t)(bn + m) * K + k0 + k8 * 8, &Bs[s * 8]);
    }
    __syncthreads();
#pragma unroll
    for (int ks = 0; ks < 2; ++ks) {
      const int k8 = ks * 4 + quad;
      u16x8 af[4], bf[2];
#pragma unroll
      for (int i = 0; i < 4; ++i) {
        int m = i * 16 + l15;
        af[i] = *(const u16x8*)(&As[(m * 8 + (k8 ^ (m & 7))) * 8]);
      }
#pragma unroll
      for (int i = 0; i < 2; ++i) {
        int n = wave * 32 + i * 16 + l15;
        bf[i] = *(const u16x8*)(&Bs[(n * 8 + (k8 ^ (n & 7))) * 8]);
      }
#pragma unroll
      for (int mi = 0; mi < 4; ++mi)
#pragma unroll
        for (int ni = 0; ni < 2; ++ni)
          acc[mi][ni] = mfma16(af[mi], bf[ni], acc[mi][ni]);
    }
  }

#pragma unroll
  for (int mi = 0; mi < 4; ++mi)
#pragma unroll
    for (int ni = 0; ni < 2; ++ni)
#pragma unroll
      for (int r = 0; r < 4; ++r) {
        int row = bm + mi * 16 + quad * 4 + r;
        int col = bn + wave * 32 + ni * 16 + l15;
        out[(size_t)row * 1024 + col] = acc[mi][ni][r] + bo[col];
      }
}

// ---------------------------------------------------------------------------
// Split-K flash attention, fixed-max softmax. Grid (64 bh, 8 qblk), block 256.
// Wave w covers keys {w*64 + 256t}, t=0..7; no barriers in the main loop.
// Q/K/V are in FRAGMENT-MAJOR layout: each fragment load is one contiguous
// 1KB wave-load (was a 16-cache-line gather). kf single-buffered, reloaded at
// qg==3 right after last use. launch_bounds(256,1): VGPR cap 512 -> no spills.
// PS: p_lds row stride in u16. MUST be == 0 mod 8 (16 B) -- P fragments are
// read as u16x8 (ds_read_b128); any other stride misaligns odd q-rows.
#define PS 72
__global__ __launch_bounds__(256, 1)
void attn_kernel(const unsigned short* __restrict__ Q,   // frag-major [64][32][8][16][8]
                 const unsigned short* __restrict__ K,   // frag-major [64][128][8][16][8]
                 const unsigned short* __restrict__ Vt,  // frag-major [64][32][4][8][16][8]
                 const int* __restrict__ mask,           // [4][2048]
                 unsigned short* __restrict__ O) {       // [4][512][1024]
  __shared__ float bias_lds[2048];
  __shared__ __align__(16) unsigned short p_lds[4][2][16 * PS];
  __shared__ float l_lds[4][64];
  __shared__ __align__(16) float o_comb[64][68];

  const int tid = threadIdx.x;
  const int wave = tid >> 6, lane = tid & 63;
  const int l15 = lane & 15, quad = lane >> 4;
  const int bh = blockIdx.x, b = bh >> 4, h = bh & 15;
  const int q0 = blockIdx.y * 64;

  {  // mask -> additive bias in log2 units, with fixed max-shift -8 folded in
    const int* mb = mask + b * 2048;
    for (int i = tid; i < 2048; i += 256)
      bias_lds[i] = mb[i] ? -8.f : -1e30f;
  }
  __syncthreads();

  const unsigned short* Qb = Q + (size_t)bh * 32768 + (size_t)(q0 >> 4) * 1024;
  const unsigned short* Kb = K + (size_t)bh * 131072;
  const unsigned short* Vb = Vt + (size_t)bh * 131072;

  // Q fragments (frag-major): one contiguous 1KB wave-load each.
  u16x8 aq[4][2];
#pragma unroll
  for (int qg = 0; qg < 4; ++qg)
#pragma unroll
    for (int ks = 0; ks < 2; ++ks)
      aq[qg][ks] = *(const u16x8*)(Qb + ((qg * 8 + ks * 4 + quad) * 16 + l15) * 8);

  f32x4 o_acc[4][4] = {};
  float l_s[4] = {0.f, 0.f, 0.f, 0.f};

  u16x8 kf[2][4];

  auto load_k = [&](int kb) {
    const int kg0 = kb >> 4;
#pragma unroll
    for (int ns = 0; ns < 4; ++ns)
#pragma unroll
      for (int ks = 0; ks < 2; ++ks)
        kf[ks][ns] = *(const u16x8*)(Kb + (((size_t)(kg0 + ns) * 8 + ks * 4 + quad) * 16 + l15) * 8);
  };

  load_k(wave * 64);

#pragma unroll 1
  for (int t = 0; t < 8; ++t) {
    const int kb = wave * 64 + t * 256;
    const int kb_next = kb + (t < 7 ? 256 : 0);

    // V^T frags (frag-major, contiguous): consumed in PV, well after issue.
    u16x8 vf[2][4];
    const int kt4 = (kb >> 6) * 4;
#pragma unroll
    for (int nd = 0; nd < 4; ++nd)
#pragma unroll
      for (int ks = 0; ks < 2; ++ks)
        vf[ks][nd] = *(const u16x8*)(Vb + (((size_t)(kt4 + nd) * 8 + ks * 4 + quad) * 16 + l15) * 8);
    f32x4 bfr[4];
#pragma unroll
    for (int ns = 0; ns < 4; ++ns)
      bfr[ns] = *(const f32x4*)&bias_lds[kb + ns * 16 + quad * 4];

#pragma unroll
    for (int qg = 0; qg < 4; ++qg) {
      // S^T tile: D[key = ns*16+quad*4+r][q = l15], C-init = bias (-8 shift)
      f32x4 sfr[4];
#pragma unroll
      for (int ns = 0; ns < 4; ++ns) {
        f32x4 sa = bfr[ns];
#pragma unroll
        for (int ks = 0; ks < 2; ++ks)
          sa = mfma16(kf[ks][ns], aq[qg][ks], sa);
        sfr[ns] = sa;
      }

      // kf dead after qg==3's S: reload for next tile now (covered by the
      // remaining softmax + PV of this qg).
      if (qg == 3) load_k(kb_next);

      float rsum = 0.f;
#pragma unroll
      for (int ns = 0; ns < 4; ++ns) {
        unsigned int pr[4];
#pragma unroll
        for (int r = 0; r < 4; ++r) {
          float p = exp2_fast(sfr[ns][r]);
          unsigned int u = __builtin_bit_cast(unsigned int, p) & 0xffff0000u;
          rsum += __builtin_bit_cast(float, u);  // sum TRUNCATED p: consistent with PV
          pr[r] = u;
        }
        uint2 pw;
        pw.x = __builtin_amdgcn_perm(pr[1], pr[0], 0x07060302u);
        pw.y = __builtin_amdgcn_perm(pr[3], pr[2], 0x07060302u);
        *(uint2*)&p_lds[wave][qg & 1][l15 * PS + ns * 16 + quad * 4] = pw;
      }
      rsum += __shfl_xor(rsum, 16, 64);
      rsum += __shfl_xor(rsum, 32, 64);
      l_s[qg] += rsum;

      // PV: A = P (lane=q, elems=key) from p_lds; B = V^T frags
#pragma unroll
      for (int ks = 0; ks < 2; ++ks) {
        u16x8 pf = *(const u16x8*)&p_lds[wave][qg & 1][l15 * PS + ks * 32 + quad * 8];
#pragma unroll
        for (int nd = 0; nd < 4; ++nd)
          o_acc[qg][nd] = mfma16(pf, vf[ks][nd], o_acc[qg][nd]);
      }
    }
  }

  // ---- combine the 4 waves' partial (l, o): plain sums (fixed max) ----
  if (quad == 0) {
#pragma unroll
    for (int qg = 0; qg < 4; ++qg)
      l_lds[wave][qg * 16 + l15] = l_s[qg];
  }
  __syncthreads();

  for (int w = 0; w < 4; ++w) {
    if (wave == w) {
#pragma unroll
      for (int qg = 0; qg < 4; ++qg)
#pragma unroll
        for (int r = 0; r < 4; ++r) {
          const int q = qg * 16 + quad * 4 + r;
#pragma unroll
          for (int nd = 0; nd < 4; ++nd) {
            const int d = nd * 16 + l15;
            float v = o_acc[qg][nd][r];
            if (w == 0) o_comb[q][d] = v;
            else        o_comb[q][d] += v;
          }
        }
    }
    __syncthreads();
  }

  // ---- final normalize + store (two u16x8 per thread) ----
  {
    const int q = tid >> 2, dc = (tid & 3) * 16;
    const float inv = 1.f / (l_lds[0][q] + l_lds[1][q] + l_lds[2][q] + l_lds[3][q]);
    unsigned short* Ob = O + ((size_t)(b * 512 + q0 + q)) * 1024 + h * 64 + dc;
    u16x8 o1, o2;
#pragma unroll
    for (int j = 0; j < 8; ++j) o1[j] = f2bf(o_comb[q][dc + j] * inv);
#pragma unroll
    for (int j = 0; j < 8; ++j) o2[j] = f2bf(o_comb[q][dc + 8 + j] * inv);
    *(u16x8*)(Ob) = o1;
    *(u16x8*)(Ob + 8) = o2;
  }
}

// ---------------------------------------------------------------------------
extern "C" void kernel_launch(void* const* d_in, const int* in_sizes, int n_in,
                              void* d_out, int out_size, void* d_ws, size_t ws_size,
                              hipStream_t stream) {
  const float* x   = (const float*)d_in[0];
  const float* ctx = (const float*)d_in[1];
  const int* mask  = (const int*)d_in[2];
  const float* Wq  = (const float*)d_in[3];
  const float* bq  = (const float*)d_in[4];
  const float* Wk  = (const float*)d_in[5];
  const float* bk  = (const float*)d_in[6];
  const float* Wv  = (const float*)d_in[7];
  const float* bv  = (const float*)d_in[8];
  const float* Wo  = (const float*)d_in[9];
  const float* bo  = (const float*)d_in[10];

  char* ws = (char*)d_ws;
  // [MB] xb 0-4, cb 4-20, w 20-28, qh 28-32, kh 32-48, vt 48-64, ah 64-68.
  unsigned short* xb  = (unsigned short*)(ws + ((size_t)0  << 20));
  unsigned short* cb  = (unsigned short*)(ws + ((size_t)4  << 20));
  unsigned short* wqb = (unsigned short*)(ws + ((size_t)20 << 20));
  unsigned short* wkb = (unsigned short*)(ws + ((size_t)22 << 20));
  unsigned short* wvb = (unsigned short*)(ws + ((size_t)24 << 20));
  unsigned short* wob = (unsigned short*)(ws + ((size_t)26 << 20));
  unsigned short* qh  = (unsigned short*)(ws + ((size_t)28 << 20));
  unsigned short* kh  = (unsigned short*)(ws + ((size_t)32 << 20));
  unsigned short* vt  = (unsigned short*)(ws + ((size_t)48 << 20));
  unsigned short* ah  = (unsigned short*)(ws + ((size_t)64 << 20));

  cast_fused<<<14336, 256, 0, stream>>>(x, ctx, Wq, Wk, Wv, Wo,
                                        xb, cb, wqb, wkb, wvb, wob);
  gemm_qkv<<<dim3(64, 10), 256, 0, stream>>>(xb, cb, wqb, wkb, wvb,
                                             bq, bk, bv, qh, kh, vt);
  attn_kernel<<<dim3(64, 8), 256, 0, stream>>>(qh, kh, vt, mask, ah);
  gemm_o<<<dim3(32, 8), 256, 0, stream>>>(ah, wob, bo, (float*)d_out);
}

// Round 10
// 204.523 us; speedup vs baseline: 1.0952x; 1.0366x over previous
//
#include <hip/hip_runtime.h>
#include <hip/hip_bf16.h>
#include <stdint.h>

// ---------------------------------------------------------------------------
// CrossAttention B=4 N=512 M=2048 C=1024 H=16 D=64, bf16 MFMA fp32 accum.
// R10: exploit ~50% key mask sparsity (varlen compaction). compact_mask
// builds per-batch valid-key index lists + cnt; ctx cast gathers valid rows
// (zero-fills the pad to the next 256); K/V GEMM row-blocks beyond
// cnt_pad256 exit; attention iterates T=(cnt+255)/256 key tiles (4-5 vs 8).
// Softmax over the same valid set (permutation-invariant) => same numerics.
// cnt/idx live at the head of d_out (gemm_o overwrites at the end).
// Carried: R9 frag-major Q/K/V layout, fixed-max softmax, dual K+V blocks.
// ---------------------------------------------------------------------------

typedef __attribute__((ext_vector_type(4))) float f32x4;
typedef __attribute__((ext_vector_type(8))) __bf16 bf16x8;
typedef __attribute__((ext_vector_type(8))) unsigned short u16x8;

#define DEVI __device__ __forceinline__

// SCALE * log2(e): folded into Wq cast so QK^T scores land in log2 units.
#define QSC (0.125f * 1.44269504088896f)

DEVI f32x4 mfma16(u16x8 a, u16x8 b, f32x4 c) {
  return __builtin_amdgcn_mfma_f32_16x16x32_bf16(
      __builtin_bit_cast(bf16x8, a), __builtin_bit_cast(bf16x8, b), c, 0, 0, 0);
}

// round-to-nearest-even fp32 -> bf16
DEVI unsigned short f2bf(float f) {
  union { float f; unsigned int u; } x; x.f = f;
  unsigned int u = x.u;
  return (unsigned short)((u + 0x7fffu + ((u >> 16) & 1u)) >> 16);
}

DEVI float exp2_fast(float x) {
#if __has_builtin(__builtin_amdgcn_exp2f)
  return __builtin_amdgcn_exp2f(x);
#else
  return exp2f(x);
#endif
}

// async global->LDS, 16 bytes per lane (global_load_lds_dwordx4)
DEVI void llds16(const void* g, void* l) {
  __builtin_amdgcn_global_load_lds(
      (const __attribute__((address_space(1))) void*)g,
      (__attribute__((address_space(3))) void*)l, 16, 0, 0);
}

// ---------------------------------------------------------------------------
// Per-batch mask compaction: idx[b][j] = original position of j-th valid key,
// cnt[b] = number of valid keys. Grid (4), block 256.
__global__ __launch_bounds__(256)
void compact_mask(const int* __restrict__ mask, int* __restrict__ cnt,
                  int* __restrict__ idx) {
  __shared__ int psum[256];
  const int b = blockIdx.x, tid = threadIdx.x;
  const int* mb = mask + b * 2048;
  int v[8], s = 0;
#pragma unroll
  for (int j = 0; j < 8; ++j) { v[j] = (mb[tid * 8 + j] != 0); s += v[j]; }
  psum[tid] = s;
  __syncthreads();
  // inclusive Hillis-Steele scan over 256 partials
  for (int off = 1; off < 256; off <<= 1) {
    int t = (tid >= off) ? psum[tid - off] : 0;
    __syncthreads();
    psum[tid] += t;
    __syncthreads();
  }
  int base = tid ? psum[tid - 1] : 0;
#pragma unroll
  for (int j = 0; j < 8; ++j)
    if (v[j]) { idx[b * 2048 + base] = tid * 8 + j; ++base; }
  if (tid == 255) cnt[b] = psum[255];
}

// ---------------------------------------------------------------------------
// Casts all fp32 inputs to bf16. Wq gets QSC folded in. ctx rows are
// GATHERED through idx (compacted); rows [cnt, cnt_pad256) zero-filled.
__global__ __launch_bounds__(256)
void cast_fused(const float* __restrict__ x, const float* __restrict__ ctx,
                const float* __restrict__ wq, const float* __restrict__ wk,
                const float* __restrict__ wv, const float* __restrict__ wo,
                const int* __restrict__ cnt, const int* __restrict__ idx,
                unsigned short* __restrict__ xb, unsigned short* __restrict__ cb,
                unsigned short* __restrict__ wqb, unsigned short* __restrict__ wkb,
                unsigned short* __restrict__ wvb, unsigned short* __restrict__ wob) {
  int bid = blockIdx.x;
  const int tid = threadIdx.x;
  if (bid >= 2048 && bid < 10240) {  // ctx: one block per compacted row
    int r = bid - 2048;
    int b = r >> 11, j = r & 2047;
    int c = cnt[b];
    unsigned short* dst = cb + (size_t)r * 1024 + tid * 4;
    if (j >= c) {
      if (j < ((c + 255) & ~255)) {  // zero pad up to next 256 boundary
        ushort4 z; z.x = z.y = z.z = z.w = 0;
        *(ushort4*)dst = z;
      }
      return;
    }
    const float* src = ctx + ((size_t)(b * 2048 + idx[b * 2048 + j])) * 1024 + tid * 4;
    const float4 v = *(const float4*)src;
    ushort4 o;
    o.x = f2bf(v.x); o.y = f2bf(v.y); o.z = f2bf(v.z); o.w = f2bf(v.w);
    *(ushort4*)dst = o;
    return;
  }
  const float* src; unsigned short* dst; float scale = 1.f;
  if (bid < 2048)        { src = x;   dst = xb; }
  else if (bid < 11264)  { src = wq;  dst = wqb; bid -= 10240; scale = QSC; }
  else if (bid < 12288)  { src = wk;  dst = wkb; bid -= 11264; }
  else if (bid < 13312)  { src = wv;  dst = wvb; bid -= 12288; }
  else                   { src = wo;  dst = wob; bid -= 13312; }
  int e = (bid * 256 + tid) * 4;
  const float4 v = *(const float4*)(src + e);
  ushort4 o;
  o.x = f2bf(v.x * scale); o.y = f2bf(v.y * scale);
  o.z = f2bf(v.z * scale); o.w = f2bf(v.w * scale);
  *(ushort4*)(dst + e) = o;
}

// ---------------------------------------------------------------------------
// Epilogue helper: stage a 128x128 bf16 C tile through LDS, store coalesced.
// mode 0: fragment-major [bh][grp=idx/16][d8][idx&15][8] (bh-extent S=1<<logS).
// mode 2: V^T fragment-major [bh][key/64][d/16][key8][d&15][8].
DEVI void epi_store(f32x4 (&acc)[4][4], const float* __restrict__ bias,
                    float bscale, void* __restrict__ Cout,
                    int bm, int bn, int logS, int mode,
                    unsigned short* cst, int tid, int wave, int l15, int quad) {
  const int wm = wave & 1, wn = wave >> 1;
  __syncthreads();
  for (int half = 0; half < 2; ++half) {
    if (wm == half) {
#pragma unroll
      for (int mi = 0; mi < 4; ++mi)
#pragma unroll
        for (int ni = 0; ni < 4; ++ni)
#pragma unroll
          for (int r = 0; r < 4; ++r) {
            int lrow = mi * 16 + quad * 4 + r;          // 0..63
            int lcol = wn * 64 + ni * 16 + l15;         // 0..127
            unsigned short bv = f2bf(acc[mi][ni][r] + bias[bn + lcol] * bscale);
            if (mode == 0) cst[lrow * 136 + lcol] = bv;
            else           cst[lcol * 72 + lrow] = bv;  // transposed
          }
    }
    __syncthreads();
    if (mode == 0) {
      // fragment-major: one u16x8 = (idx fixed, 8 consecutive d)
      int lrow = tid >> 2, cc = (tid & 3) * 32;
      int row = bm + half * 64 + lrow;
      int S = 1 << logS;
      int b = row >> logS, sl = row & (S - 1);
#pragma unroll
      for (int j = 0; j < 4; ++j) {
        int col = bn + cc + j * 8;
        int h = col >> 6, d8 = (col & 63) >> 3;
        size_t base = (((size_t)(b * 16 + h)) << logS) * 64 +
                      (size_t)(sl >> 4) * 1024 + d8 * 128 + (sl & 15) * 8;
        *(u16x8*)&((unsigned short*)Cout)[base] =
            *(const u16x8*)&cst[lrow * 136 + cc + j * 8];
      }
    } else {
      // V^T fragment-major: one u16x8 = (d fixed, 8 consecutive keys)
      int c = tid >> 1, rc = (tid & 1) * 32;
      int gc = bn + c, h = gc >> 6, d = gc & 63;
      int b = bm >> 11;
#pragma unroll
      for (int j = 0; j < 4; ++j) {
        int key = (bm & 2047) + half * 64 + rc + j * 8;
        size_t base = (size_t)(b * 16 + h) * 131072 +
                      (size_t)(((key >> 6) * 4 + (d >> 4)) * 8 + ((key >> 3) & 7)) * 128 +
                      (d & 15) * 8;
        *(u16x8*)&((unsigned short*)Cout)[base] =
            *(const u16x8*)&cst[c * 72 + rc + j * 8];
      }
    }
    __syncthreads();
  }
}

// ---------------------------------------------------------------------------
// Fused K+V body: both GEMMs read the same A rows; stage A once per K-step,
// run Wk and Wv tiles against it. 64 MFMA per barrier pair.
DEVI void kv_body(const unsigned short* __restrict__ A,
                  const unsigned short* __restrict__ WK,
                  const unsigned short* __restrict__ WV,
                  const float* __restrict__ bk, const float* __restrict__ bv,
                  unsigned short* __restrict__ kh, unsigned short* __restrict__ vt,
                  int bm, int bn, unsigned short* sh) {
  constexpr int K = 1024;
  unsigned short* As = sh;
  unsigned short* Ks = sh + 128 * 64;
  unsigned short* Vs = sh + 2 * 128 * 64;

  const int tid = threadIdx.x;
  const int wave = tid >> 6, lane = tid & 63;
  const int l15 = lane & 15, quad = lane >> 4;
  const int wm = wave & 1, wn = wave >> 1;

  f32x4 ak[4][4] = {}, av[4][4] = {};

  for (int k0 = 0; k0 < K; k0 += 64) {
    __syncthreads();
#pragma unroll
    for (int c = 0; c < 4; ++c) {
      int s = c * 256 + tid;
      int m = s >> 3;
      int k8 = (s & 7) ^ (m & 7);
      llds16(A + (size_t)(bm + m) * K + k0 + k8 * 8, &As[s * 8]);
      llds16(WK + (size_t)(bn + m) * K + k0 + k8 * 8, &Ks[s * 8]);
      llds16(WV + (size_t)(bn + m) * K + k0 + k8 * 8, &Vs[s * 8]);
    }
    __syncthreads();
#pragma unroll
    for (int ks = 0; ks < 2; ++ks) {
      const int k8 = ks * 4 + quad;
      u16x8 af[4], bf[4];
#pragma unroll
      for (int i = 0; i < 4; ++i) {
        int m = wm * 64 + i * 16 + l15;
        af[i] = *(const u16x8*)(&As[(m * 8 + (k8 ^ (m & 7))) * 8]);
      }
#pragma unroll
      for (int i = 0; i < 4; ++i) {
        int n = wn * 64 + i * 16 + l15;
        bf[i] = *(const u16x8*)(&Ks[(n * 8 + (k8 ^ (n & 7))) * 8]);
      }
#pragma unroll
      for (int mi = 0; mi < 4; ++mi)
#pragma unroll
        for (int ni = 0; ni < 4; ++ni)
          ak[mi][ni] = mfma16(af[mi], bf[ni], ak[mi][ni]);
#pragma unroll
      for (int i = 0; i < 4; ++i) {
        int n = wn * 64 + i * 16 + l15;
        bf[i] = *(const u16x8*)(&Vs[(n * 8 + (k8 ^ (n & 7))) * 8]);
      }
#pragma unroll
      for (int mi = 0; mi < 4; ++mi)
#pragma unroll
        for (int ni = 0; ni < 4; ++ni)
          av[mi][ni] = mfma16(af[mi], bf[ni], av[mi][ni]);
    }
  }

  epi_store(ak, bk, 1.f, kh, bm, bn, 11, 0, sh, tid, wave, l15, quad);
  epi_store(av, bv, 1.f, vt, bm, bn, 11, 2, sh, tid, wave, l15, quad);
}

// Single-GEMM body (Q projection), mode 0 epilogue.
DEVI void q_body(const unsigned short* __restrict__ A,
                 const unsigned short* __restrict__ W,
                 const float* __restrict__ bias,
                 unsigned short* __restrict__ Cout,
                 int bm, int bn, unsigned short* sh) {
  constexpr int K = 1024;
  unsigned short* As = sh;
  unsigned short* Bs = sh + 128 * 64;

  const int tid = threadIdx.x;
  const int wave = tid >> 6, lane = tid & 63;
  const int l15 = lane & 15, quad = lane >> 4;
  const int wm = wave & 1, wn = wave >> 1;

  f32x4 acc[4][4] = {};

  for (int k0 = 0; k0 < K; k0 += 64) {
    __syncthreads();
#pragma unroll
    for (int c = 0; c < 4; ++c) {
      int s = c * 256 + tid;
      int m = s >> 3;
      int k8 = (s & 7) ^ (m & 7);
      llds16(A + (size_t)(bm + m) * K + k0 + k8 * 8, &As[s * 8]);
      llds16(W + (size_t)(bn + m) * K + k0 + k8 * 8, &Bs[s * 8]);
    }
    __syncthreads();
#pragma unroll
    for (int ks = 0; ks < 2; ++ks) {
      const int k8 = ks * 4 + quad;
      u16x8 af[4], bf[4];
#pragma unroll
      for (int i = 0; i < 4; ++i) {
        int m = wm * 64 + i * 16 + l15;
        af[i] = *(const u16x8*)(&As[(m * 8 + (k8 ^ (m & 7))) * 8]);
        int n = wn * 64 + i * 16 + l15;
        bf[i] = *(const u16x8*)(&Bs[(n * 8 + (k8 ^ (n & 7))) * 8]);
      }
#pragma unroll
      for (int mi = 0; mi < 4; ++mi)
#pragma unroll
        for (int ni = 0; ni < 4; ++ni)
          acc[mi][ni] = mfma16(af[mi], bf[ni], acc[mi][ni]);
    }
  }

  epi_store(acc, bias, QSC, Cout, bm, bn, 9, 0, sh, tid, wave, l15, quad);
}

// Fused Q/K/V projection. Grid (64, 10): y<8 K+V duals (skip row-blocks past
// the compacted count), y in {8,9} Q singles dispatched last (short tail).
__global__ __launch_bounds__(256, 2)
void gemm_qkv(const unsigned short* __restrict__ xb,
              const unsigned short* __restrict__ cb,
              const unsigned short* __restrict__ wq,
              const unsigned short* __restrict__ wk,
              const unsigned short* __restrict__ wv,
              const float* __restrict__ bq, const float* __restrict__ bk,
              const float* __restrict__ bv,
              const int* __restrict__ cnt,
              unsigned short* __restrict__ qh, unsigned short* __restrict__ kh,
              unsigned short* __restrict__ vt) {
  __shared__ __align__(16) unsigned short sh[128 * 64 * 3];  // 48 KB
  const int x = blockIdx.x, y = blockIdx.y;
  if (y < 8) {
    const int bm = x * 128;
    const int cpad = (cnt[bm >> 11] + 255) & ~255;
    if ((bm & 2047) >= cpad) return;  // whole key tile masked out
    kv_body(cb, wk, wv, bk, bv, kh, vt, bm, y * 128, sh);
  } else {
    q_body(xb, wq, bq, qh, (x & 15) * 128, (y - 8) * 512 + (x >> 4) * 128, sh);
  }
}

// ---------------------------------------------------------------------------
// Output projection: out[2048,1024] fp32 = ah @ Wo^T + bo. 64x128 tile,
// grid (32, 8) = 256 blocks (one per CU), 4 waves each 64 rows x 32 cols.
__global__ __launch_bounds__(256)
void gemm_o(const unsigned short* __restrict__ A,
            const unsigned short* __restrict__ W,
            const float* __restrict__ bo, float* __restrict__ out) {
  constexpr int K = 1024;
  __shared__ __align__(16) unsigned short As[64 * 64];   // 8 KB
  __shared__ __align__(16) unsigned short Bs[128 * 64];  // 16 KB

  const int tid = threadIdx.x;
  const int wave = tid >> 6, lane = tid & 63;
  const int l15 = lane & 15, quad = lane >> 4;
  const int bm = blockIdx.x * 64, bn = blockIdx.y * 128;

  f32x4 acc[4][2] = {};

  for (int k0 = 0; k0 < K; k0 += 64) {
    __syncthreads();
#pragma unroll
    for (int c = 0; c < 2; ++c) {
      int s = c * 256 + tid;
      int m = s >> 3, k8 = (s & 7) ^ (m & 7);
      llds16(A + (size_t)(bm + m) * K + k0 + k8 * 8, &As[s * 8]);
    }
#pragma unroll
    for (int c = 0; c < 4; ++c) {
      int s = c * 256 + tid;
      int m = s >> 3, k8 = (s & 7) ^ (m & 7);
      llds16(W + (size_t)(bn + m) * K + k0 + k8 * 8, &Bs[s * 8]);
    }
    __syncthreads();
#pragma unroll
    for (int ks = 0; ks < 2; ++ks) {
      const int k8 = ks * 4 + quad;
      u16x8 af[4], bf[2];
#pragma unroll
      for (int i = 0; i < 4; ++i) {
        int m = i * 16 + l15;
        af[i] = *(const u16x8*)(&As[(m * 8 + (k8 ^ (m & 7))) * 8]);
      }
#pragma unroll
      for (int i = 0; i < 2; ++i) {
        int n = wave * 32 + i * 16 + l15;
        bf[i] = *(const u16x8*)(&Bs[(n * 8 + (k8 ^ (n & 7))) * 8]);
      }
#pragma unroll
      for (int mi = 0; mi < 4; ++mi)
#pragma unroll
        for (int ni = 0; ni < 2; ++ni)
          acc[mi][ni] = mfma16(af[mi], bf[ni], acc[mi][ni]);
    }
  }

#pragma unroll
  for (int mi = 0; mi < 4; ++mi)
#pragma unroll
    for (int ni = 0; ni < 2; ++ni)
#pragma unroll
      for (int r = 0; r < 4; ++r) {
        int row = bm + mi * 16 + quad * 4 + r;
        int col = bn + wave * 32 + ni * 16 + l15;
        out[(size_t)row * 1024 + col] = acc[mi][ni][r] + bo[col];
      }
}

// ---------------------------------------------------------------------------
// Split-K flash attention over COMPACTED keys, fixed-max softmax.
// Grid (64 bh, 8 qblk), block 256. Wave w covers keys {w*64 + 256t},
// t < T = ceil(cnt/256); keys in [cnt, T*256) get bias -1e30 (P=0; their K/V
// rows come from zero-padded ctx rows -> finite). No barriers in main loop.
// Q/K/V are FRAGMENT-MAJOR: each fragment load is one contiguous 1KB wave-load.
// PS: p_lds row stride in u16. MUST be == 0 mod 8 (16 B) -- P fragments are
// read as u16x8 (ds_read_b128); any other stride misaligns odd q-rows.
#define PS 72
__global__ __launch_bounds__(256, 1)
void attn_kernel(const unsigned short* __restrict__ Q,   // frag-major [64][32][8][16][8]
                 const unsigned short* __restrict__ K,   // frag-major [64][128][8][16][8]
                 const unsigned short* __restrict__ Vt,  // frag-major [64][32][4][8][16][8]
                 const int* __restrict__ cnt,            // [4] valid-key counts
                 unsigned short* __restrict__ O) {       // [4][512][1024]
  __shared__ float bias_lds[2048];
  __shared__ __align__(16) unsigned short p_lds[4][2][16 * PS];
  __shared__ float l_lds[4][64];
  __shared__ __align__(16) float o_comb[64][68];

  const int tid = threadIdx.x;
  const int wave = tid >> 6, lane = tid & 63;
  const int l15 = lane & 15, quad = lane >> 4;
  const int bh = blockIdx.x, b = bh >> 4, h = bh & 15;
  const int q0 = blockIdx.y * 64;

  const int c = cnt[b];
  const int T = (c + 255) >> 8;  // number of 256-key macro tiles

  // compacted keys are all valid: -8 fixed max-shift; pad keys -> -1e30
  for (int i = tid; i < 2048; i += 256)
    bias_lds[i] = (i < c) ? -8.f : -1e30f;
  __syncthreads();

  const unsigned short* Qb = Q + (size_t)bh * 32768 + (size_t)(q0 >> 4) * 1024;
  const unsigned short* Kb = K + (size_t)bh * 131072;
  const unsigned short* Vb = Vt + (size_t)bh * 131072;

  // Q fragments (frag-major): one contiguous 1KB wave-load each.
  u16x8 aq[4][2];
#pragma unroll
  for (int qg = 0; qg < 4; ++qg)
#pragma unroll
    for (int ks = 0; ks < 2; ++ks)
      aq[qg][ks] = *(const u16x8*)(Qb + ((qg * 8 + ks * 4 + quad) * 16 + l15) * 8);

  f32x4 o_acc[4][4] = {};
  float l_s[4] = {0.f, 0.f, 0.f, 0.f};

  u16x8 kf[2][4];

  auto load_k = [&](int kb) {
    const int kg0 = kb >> 4;
#pragma unroll
    for (int ns = 0; ns < 4; ++ns)
#pragma unroll
      for (int ks = 0; ks < 2; ++ks)
        kf[ks][ns] = *(const u16x8*)(Kb + (((size_t)(kg0 + ns) * 8 + ks * 4 + quad) * 16 + l15) * 8);
  };

  load_k(wave * 64);

#pragma unroll 1
  for (int t = 0; t < T; ++t) {
    const int kb = wave * 64 + t * 256;
    const int kb_next = kb + (t + 1 < T ? 256 : 0);

    // V^T frags (frag-major, contiguous): consumed in PV, well after issue.
    u16x8 vf[2][4];
    const int kt4 = (kb >> 6) * 4;
#pragma unroll
    for (int nd = 0; nd < 4; ++nd)
#pragma unroll
      for (int ks = 0; ks < 2; ++ks)
        vf[ks][nd] = *(const u16x8*)(Vb + (((size_t)(kt4 + nd) * 8 + ks * 4 + quad) * 16 + l15) * 8);
    f32x4 bfr[4];
#pragma unroll
    for (int ns = 0; ns < 4; ++ns)
      bfr[ns] = *(const f32x4*)&bias_lds[kb + ns * 16 + quad * 4];

#pragma unroll
    for (int qg = 0; qg < 4; ++qg) {
      // S^T tile: D[key = ns*16+quad*4+r][q = l15], C-init = bias (-8 shift)
      f32x4 sfr[4];
#pragma unroll
      for (int ns = 0; ns < 4; ++ns) {
        f32x4 sa = bfr[ns];
#pragma unroll
        for (int ks = 0; ks < 2; ++ks)
          sa = mfma16(kf[ks][ns], aq[qg][ks], sa);
        sfr[ns] = sa;
      }

      // kf dead after qg==3's S: reload for next tile now (covered by the
      // remaining softmax + PV of this qg).
      if (qg == 3) load_k(kb_next);

      float rsum = 0.f;
#pragma unroll
      for (int ns = 0; ns < 4; ++ns) {
        unsigned int pr[4];
#pragma unroll
        for (int r = 0; r < 4; ++r) {
          float p = exp2_fast(sfr[ns][r]);
          unsigned int u = __builtin_bit_cast(unsigned int, p) & 0xffff0000u;
          rsum += __builtin_bit_cast(float, u);  // sum TRUNCATED p: consistent with PV
          pr[r] = u;
        }
        uint2 pw;
        pw.x = __builtin_amdgcn_perm(pr[1], pr[0], 0x07060302u);
        pw.y = __builtin_amdgcn_perm(pr[3], pr[2], 0x07060302u);
        *(uint2*)&p_lds[wave][qg & 1][l15 * PS + ns * 16 + quad * 4] = pw;
      }
      rsum += __shfl_xor(rsum, 16, 64);
      rsum += __shfl_xor(rsum, 32, 64);
      l_s[qg] += rsum;

      // PV: A = P (lane=q, elems=key) from p_lds; B = V^T frags
#pragma unroll
      for (int ks = 0; ks < 2; ++ks) {
        u16x8 pf = *(const u16x8*)&p_lds[wave][qg & 1][l15 * PS + ks * 32 + quad * 8];
#pragma unroll
        for (int nd = 0; nd < 4; ++nd)
          o_acc[qg][nd] = mfma16(pf, vf[ks][nd], o_acc[qg][nd]);
      }
    }
  }

  // ---- combine the 4 waves' partial (l, o): plain sums (fixed max) ----
  if (quad == 0) {
#pragma unroll
    for (int qg = 0; qg < 4; ++qg)
      l_lds[wave][qg * 16 + l15] = l_s[qg];
  }
  __syncthreads();

  for (int w = 0; w < 4; ++w) {
    if (wave == w) {
#pragma unroll
      for (int qg = 0; qg < 4; ++qg)
#pragma unroll
        for (int r = 0; r < 4; ++r) {
          const int q = qg * 16 + quad * 4 + r;
#pragma unroll
          for (int nd = 0; nd < 4; ++nd) {
            const int d = nd * 16 + l15;
            float v = o_acc[qg][nd][r];
            if (w == 0) o_comb[q][d] = v;
            else        o_comb[q][d] += v;
          }
        }
    }
    __syncthreads();
  }

  // ---- final normalize + store (two u16x8 per thread) ----
  {
    const int q = tid >> 2, dc = (tid & 3) * 16;
    const float inv = 1.f / (l_lds[0][q] + l_lds[1][q] + l_lds[2][q] + l_lds[3][q]);
    unsigned short* Ob = O + ((size_t)(b * 512 + q0 + q)) * 1024 + h * 64 + dc;
    u16x8 o1, o2;
#pragma unroll
    for (int j = 0; j < 8; ++j) o1[j] = f2bf(o_comb[q][dc + j] * inv);
#pragma unroll
    for (int j = 0; j < 8; ++j) o2[j] = f2bf(o_comb[q][dc + 8 + j] * inv);
    *(u16x8*)(Ob) = o1;
    *(u16x8*)(Ob + 8) = o2;
  }
}

// ---------------------------------------------------------------------------
extern "C" void kernel_launch(void* const* d_in, const int* in_sizes, int n_in,
                              void* d_out, int out_size, void* d_ws, size_t ws_size,
                              hipStream_t stream) {
  const float* x   = (const float*)d_in[0];
  const float* ctx = (const float*)d_in[1];
  const int* mask  = (const int*)d_in[2];
  const float* Wq  = (const float*)d_in[3];
  const float* bq  = (const float*)d_in[4];
  const float* Wk  = (const float*)d_in[5];
  const float* bk  = (const float*)d_in[6];
  const float* Wv  = (const float*)d_in[7];
  const float* bv  = (const float*)d_in[8];
  const float* Wo  = (const float*)d_in[9];
  const float* bo  = (const float*)d_in[10];

  char* ws = (char*)d_ws;
  // [MB] xb 0-4, cb 4-20, w 20-28, qh 28-32, kh 32-48, vt 48-64, ah 64-68.
  unsigned short* xb  = (unsigned short*)(ws + ((size_t)0  << 20));
  unsigned short* cb  = (unsigned short*)(ws + ((size_t)4  << 20));
  unsigned short* wqb = (unsigned short*)(ws + ((size_t)20 << 20));
  unsigned short* wkb = (unsigned short*)(ws + ((size_t)22 << 20));
  unsigned short* wvb = (unsigned short*)(ws + ((size_t)24 << 20));
  unsigned short* wob = (unsigned short*)(ws + ((size_t)26 << 20));
  unsigned short* qh  = (unsigned short*)(ws + ((size_t)28 << 20));
  unsigned short* kh  = (unsigned short*)(ws + ((size_t)32 << 20));
  unsigned short* vt  = (unsigned short*)(ws + ((size_t)48 << 20));
  unsigned short* ah  = (unsigned short*)(ws + ((size_t)64 << 20));
  // cnt[4] + idx[4][2048] live at the head of d_out (int) -- consumed by
  // cast/qkv/attn, then overwritten by gemm_o's final fp32 output.
  int* cnt = (int*)d_out;
  int* idx = (int*)d_out + 4;

  compact_mask<<<4, 256, 0, stream>>>(mask, cnt, idx);
  cast_fused<<<14336, 256, 0, stream>>>(x, ctx, Wq, Wk, Wv, Wo, cnt, idx,
                                        xb, cb, wqb, wkb, wvb, wob);
  gemm_qkv<<<dim3(64, 10), 256, 0, stream>>>(xb, cb, wqb, wkb, wvb,
                                             bq, bk, bv, cnt, qh, kh, vt);
  attn_kernel<<<dim3(64, 8), 256, 0, stream>>>(qh, kh, vt, cnt, ah);
  gemm_o<<<dim3(32, 8), 256, 0, stream>>>(ah, wob, bo, (float*)d_out);
}

// Round 12
// 190.530 us; speedup vs baseline: 1.1756x; 1.0734x over previous
//
#include <hip/hip_runtime.h>
#include <hip/hip_bf16.h>
#include <stdint.h>

// ---------------------------------------------------------------------------
// CrossAttention B=4 N=512 M=2048 C=1024 H=16 D=64, bf16 MFMA fp32 accum.
// R12: R11 minus the d_out-as-scratch hazard. R11 stored cnt/idx at the head
// of d_out; the harness poisons/validates d_out around the timed replays, and
// post-timing output diverged (first launch passed, replays off by 1.7e-2) --
// the only nondeterminism vector was cross-kernel metadata in d_out. Now:
// ctx compaction is a SCATTER (each block computes its row's rank from the
// mask in-LDS), and gemm_qkv/attn recompute cnt from the mask per block.
// d_out is written only by gemm_o. Numerics identical to R10/R11.
// Carried: dense qkv grid remap, varlen compaction, frag-major Q/K/V,
// fixed-max softmax w/ register bias, dual K+V blocks, launch_bounds(256,2).
// ---------------------------------------------------------------------------

typedef __attribute__((ext_vector_type(4))) float f32x4;
typedef __attribute__((ext_vector_type(8))) __bf16 bf16x8;
typedef __attribute__((ext_vector_type(8))) unsigned short u16x8;

#define DEVI __device__ __forceinline__

// SCALE * log2(e): folded into Wq cast so QK^T scores land in log2 units.
#define QSC (0.125f * 1.44269504088896f)

DEVI f32x4 mfma16(u16x8 a, u16x8 b, f32x4 c) {
  return __builtin_amdgcn_mfma_f32_16x16x32_bf16(
      __builtin_bit_cast(bf16x8, a), __builtin_bit_cast(bf16x8, b), c, 0, 0, 0);
}

// round-to-nearest-even fp32 -> bf16
DEVI unsigned short f2bf(float f) {
  union { float f; unsigned int u; } x; x.f = f;
  unsigned int u = x.u;
  return (unsigned short)((u + 0x7fffu + ((u >> 16) & 1u)) >> 16);
}

DEVI float exp2_fast(float x) {
#if __has_builtin(__builtin_amdgcn_exp2f)
  return __builtin_amdgcn_exp2f(x);
#else
  return exp2f(x);
#endif
}

// async global->LDS, 16 bytes per lane (global_load_lds_dwordx4)
DEVI void llds16(const void* g, void* l) {
  __builtin_amdgcn_global_load_lds(
      (const __attribute__((address_space(1))) void*)g,
      (__attribute__((address_space(3))) void*)l, 16, 0, 0);
}

// ---------------------------------------------------------------------------
// Casts all fp32 inputs to bf16. Wq gets QSC folded in. ctx rows are
// SCATTERED into compacted order: block for original row i computes
// (prefix-valid, total) from the mask; valid row -> slot pre, invalid row ->
// zero-fills slot c + invalid-rank while < cnt_pad256. Bijective remap; same
// compacted layout as an idx-gather, with no precomputed metadata.
__global__ __launch_bounds__(256)
void cast_fused(const float* __restrict__ x, const float* __restrict__ ctx,
                const float* __restrict__ wq, const float* __restrict__ wk,
                const float* __restrict__ wv, const float* __restrict__ wo,
                const int* __restrict__ mask,
                unsigned short* __restrict__ xb, unsigned short* __restrict__ cb,
                unsigned short* __restrict__ wqb, unsigned short* __restrict__ wkb,
                unsigned short* __restrict__ wvb, unsigned short* __restrict__ wob) {
  int bid = blockIdx.x;
  const int tid = threadIdx.x;
  if (bid >= 2048 && bid < 10240) {  // ctx: one block per ORIGINAL row
    __shared__ int red[256][2];
    int r = bid - 2048;
    int b = r >> 11, i = r & 2047;
    const int* mb = mask + b * 2048;
    int sall = 0, spre = 0;
#pragma unroll
    for (int j = 0; j < 8; ++j) {
      int p = tid * 8 + j;
      int v = (mb[p] != 0);
      sall += v;
      spre += (p < i) ? v : 0;
    }
    red[tid][0] = spre; red[tid][1] = sall;
    __syncthreads();
    for (int off = 128; off > 0; off >>= 1) {
      if (tid < off) { red[tid][0] += red[tid + off][0]; red[tid][1] += red[tid + off][1]; }
      __syncthreads();
    }
    const int pre = red[0][0], c = red[0][1];
    const int valid = (mb[i] != 0);
    int dst;
    if (valid) {
      dst = pre;                       // rank among valid, original order
    } else {
      dst = c + (i - pre);             // rank among invalid, fills the tail
      if (dst >= ((c + 255) & ~255)) return;  // beyond pad: untouched
    }
    unsigned short* dp = cb + ((size_t)(b * 2048 + dst)) * 1024 + tid * 4;
    if (valid) {
      const float4 v = *(const float4*)(ctx + ((size_t)(b * 2048 + i)) * 1024 + tid * 4);
      ushort4 o;
      o.x = f2bf(v.x); o.y = f2bf(v.y); o.z = f2bf(v.z); o.w = f2bf(v.w);
      *(ushort4*)dp = o;
    } else {
      ushort4 z; z.x = z.y = z.z = z.w = 0;
      *(ushort4*)dp = z;
    }
    return;
  }
  const float* src; unsigned short* dst; float scale = 1.f;
  if (bid < 2048)        { src = x;   dst = xb; }
  else if (bid < 11264)  { src = wq;  dst = wqb; bid -= 10240; scale = QSC; }
  else if (bid < 12288)  { src = wk;  dst = wkb; bid -= 11264; }
  else if (bid < 13312)  { src = wv;  dst = wvb; bid -= 12288; }
  else                   { src = wo;  dst = wob; bid -= 13312; }
  int e = (bid * 256 + tid) * 4;
  const float4 v = *(const float4*)(src + e);
  ushort4 o;
  o.x = f2bf(v.x * scale); o.y = f2bf(v.y * scale);
  o.z = f2bf(v.z * scale); o.w = f2bf(v.w * scale);
  *(ushort4*)(dst + e) = o;
}

// ---------------------------------------------------------------------------
// Epilogue helper: stage a 128x128 bf16 C tile through LDS, store coalesced.
// mode 0: fragment-major [bh][grp=idx/16][d8][idx&15][8] (bh-extent S=1<<logS).
// mode 2: V^T fragment-major [bh][key/64][d/16][key8][d&15][8].
DEVI void epi_store(f32x4 (&acc)[4][4], const float* __restrict__ bias,
                    float bscale, void* __restrict__ Cout,
                    int bm, int bn, int logS, int mode,
                    unsigned short* cst, int tid, int wave, int l15, int quad) {
  const int wm = wave & 1, wn = wave >> 1;
  __syncthreads();
  for (int half = 0; half < 2; ++half) {
    if (wm == half) {
#pragma unroll
      for (int mi = 0; mi < 4; ++mi)
#pragma unroll
        for (int ni = 0; ni < 4; ++ni)
#pragma unroll
          for (int r = 0; r < 4; ++r) {
            int lrow = mi * 16 + quad * 4 + r;          // 0..63
            int lcol = wn * 64 + ni * 16 + l15;         // 0..127
            unsigned short bv = f2bf(acc[mi][ni][r] + bias[bn + lcol] * bscale);
            if (mode == 0) cst[lrow * 136 + lcol] = bv;
            else           cst[lcol * 72 + lrow] = bv;  // transposed
          }
    }
    __syncthreads();
    if (mode == 0) {
      // fragment-major: one u16x8 = (idx fixed, 8 consecutive d)
      int lrow = tid >> 2, cc = (tid & 3) * 32;
      int row = bm + half * 64 + lrow;
      int S = 1 << logS;
      int b = row >> logS, sl = row & (S - 1);
#pragma unroll
      for (int j = 0; j < 4; ++j) {
        int col = bn + cc + j * 8;
        int h = col >> 6, d8 = (col & 63) >> 3;
        size_t base = (((size_t)(b * 16 + h)) << logS) * 64 +
                      (size_t)(sl >> 4) * 1024 + d8 * 128 + (sl & 15) * 8;
        *(u16x8*)&((unsigned short*)Cout)[base] =
            *(const u16x8*)&cst[lrow * 136 + cc + j * 8];
      }
    } else {
      // V^T fragment-major: one u16x8 = (d fixed, 8 consecutive keys)
      int c = tid >> 1, rc = (tid & 1) * 32;
      int gc = bn + c, h = gc >> 6, d = gc & 63;
      int b = bm >> 11;
#pragma unroll
      for (int j = 0; j < 4; ++j) {
        int key = (bm & 2047) + half * 64 + rc + j * 8;
        size_t base = (size_t)(b * 16 + h) * 131072 +
                      (size_t)(((key >> 6) * 4 + (d >> 4)) * 8 + ((key >> 3) & 7)) * 128 +
                      (d & 15) * 8;
        *(u16x8*)&((unsigned short*)Cout)[base] =
            *(const u16x8*)&cst[c * 72 + rc + j * 8];
      }
    }
    __syncthreads();
  }
}

// ---------------------------------------------------------------------------
// Fused K+V body: both GEMMs read the same A rows; stage A once per K-step,
// run Wk and Wv tiles against it. 64 MFMA per barrier pair.
DEVI void kv_body(const unsigned short* __restrict__ A,
                  const unsigned short* __restrict__ WK,
                  const unsigned short* __restrict__ WV,
                  const float* __restrict__ bk, const float* __restrict__ bv,
                  unsigned short* __restrict__ kh, unsigned short* __restrict__ vt,
                  int bm, int bn, unsigned short* sh) {
  constexpr int K = 1024;
  unsigned short* As = sh;
  unsigned short* Ks = sh + 128 * 64;
  unsigned short* Vs = sh + 2 * 128 * 64;

  const int tid = threadIdx.x;
  const int wave = tid >> 6, lane = tid & 63;
  const int l15 = lane & 15, quad = lane >> 4;
  const int wm = wave & 1, wn = wave >> 1;

  f32x4 ak[4][4] = {}, av[4][4] = {};

  for (int k0 = 0; k0 < K; k0 += 64) {
    __syncthreads();
#pragma unroll
    for (int c = 0; c < 4; ++c) {
      int s = c * 256 + tid;
      int m = s >> 3;
      int k8 = (s & 7) ^ (m & 7);
      llds16(A + (size_t)(bm + m) * K + k0 + k8 * 8, &As[s * 8]);
      llds16(WK + (size_t)(bn + m) * K + k0 + k8 * 8, &Ks[s * 8]);
      llds16(WV + (size_t)(bn + m) * K + k0 + k8 * 8, &Vs[s * 8]);
    }
    __syncthreads();
#pragma unroll
    for (int ks = 0; ks < 2; ++ks) {
      const int k8 = ks * 4 + quad;
      u16x8 af[4], bf[4];
#pragma unroll
      for (int i = 0; i < 4; ++i) {
        int m = wm * 64 + i * 16 + l15;
        af[i] = *(const u16x8*)(&As[(m * 8 + (k8 ^ (m & 7))) * 8]);
      }
#pragma unroll
      for (int i = 0; i < 4; ++i) {
        int n = wn * 64 + i * 16 + l15;
        bf[i] = *(const u16x8*)(&Ks[(n * 8 + (k8 ^ (n & 7))) * 8]);
      }
#pragma unroll
      for (int mi = 0; mi < 4; ++mi)
#pragma unroll
        for (int ni = 0; ni < 4; ++ni)
          ak[mi][ni] = mfma16(af[mi], bf[ni], ak[mi][ni]);
#pragma unroll
      for (int i = 0; i < 4; ++i) {
        int n = wn * 64 + i * 16 + l15;
        bf[i] = *(const u16x8*)(&Vs[(n * 8 + (k8 ^ (n & 7))) * 8]);
      }
#pragma unroll
      for (int mi = 0; mi < 4; ++mi)
#pragma unroll
        for (int ni = 0; ni < 4; ++ni)
          av[mi][ni] = mfma16(af[mi], bf[ni], av[mi][ni]);
    }
  }

  epi_store(ak, bk, 1.f, kh, bm, bn, 11, 0, sh, tid, wave, l15, quad);
  epi_store(av, bv, 1.f, vt, bm, bn, 11, 2, sh, tid, wave, l15, quad);
}

// Single-GEMM body (Q projection), mode 0 epilogue.
DEVI void q_body(const unsigned short* __restrict__ A,
                 const unsigned short* __restrict__ W,
                 const float* __restrict__ bias,
                 unsigned short* __restrict__ Cout,
                 int bm, int bn, unsigned short* sh) {
  constexpr int K = 1024;
  unsigned short* As = sh;
  unsigned short* Bs = sh + 128 * 64;

  const int tid = threadIdx.x;
  const int wave = tid >> 6, lane = tid & 63;
  const int l15 = lane & 15, quad = lane >> 4;
  const int wm = wave & 1, wn = wave >> 1;

  f32x4 acc[4][4] = {};

  for (int k0 = 0; k0 < K; k0 += 64) {
    __syncthreads();
#pragma unroll
    for (int c = 0; c < 4; ++c) {
      int s = c * 256 + tid;
      int m = s >> 3;
      int k8 = (s & 7) ^ (m & 7);
      llds16(A + (size_t)(bm + m) * K + k0 + k8 * 8, &As[s * 8]);
      llds16(W + (size_t)(bn + m) * K + k0 + k8 * 8, &Bs[s * 8]);
    }
    __syncthreads();
#pragma unroll
    for (int ks = 0; ks < 2; ++ks) {
      const int k8 = ks * 4 + quad;
      u16x8 af[4], bf[4];
#pragma unroll
      for (int i = 0; i < 4; ++i) {
        int m = wm * 64 + i * 16 + l15;
        af[i] = *(const u16x8*)(&As[(m * 8 + (k8 ^ (m & 7))) * 8]);
        int n = wn * 64 + i * 16 + l15;
        bf[i] = *(const u16x8*)(&Bs[(n * 8 + (k8 ^ (n & 7))) * 8]);
      }
#pragma unroll
      for (int mi = 0; mi < 4; ++mi)
#pragma unroll
        for (int ni = 0; ni < 4; ++ni)
          acc[mi][ni] = mfma16(af[mi], bf[ni], acc[mi][ni]);
    }
  }

  epi_store(acc, bias, QSC, Cout, bm, bn, 9, 0, sh, tid, wave, l15, quad);
}

// Fused Q/K/V projection, DENSE remap. Flat grid 640 blocks. cnt per batch
// is recomputed from the mask in-block (L2-hit reads; no cross-kernel state).
// ids [0, L*8)        : live K+V dual tiles (L = total live 128-row blocks)
// ids [L*8, L*8+128)  : Q single tiles (short blocks -> short tail)
// ids >= L*8+128      : exit immediately (at the END of dispatch order)
__global__ __launch_bounds__(256, 2)
void gemm_qkv(const unsigned short* __restrict__ xb,
              const unsigned short* __restrict__ cb,
              const unsigned short* __restrict__ wq,
              const unsigned short* __restrict__ wk,
              const unsigned short* __restrict__ wv,
              const float* __restrict__ bq, const float* __restrict__ bk,
              const float* __restrict__ bv,
              const int* __restrict__ mask,
              unsigned short* __restrict__ qh, unsigned short* __restrict__ kh,
              unsigned short* __restrict__ vt) {
  __shared__ __align__(16) unsigned short sh[128 * 64 * 3];  // 48 KB
  __shared__ int qsum[260];
  const int id = blockIdx.x;
  const int tid = threadIdx.x;

  {  // per-batch valid-key counts from the mask (4 x 2048 ints, L2-hit)
    int s = 0;
    const int* mp = mask + tid * 32;
#pragma unroll 8
    for (int j = 0; j < 32; ++j) s += (mp[j] != 0);
    qsum[tid] = s;
    __syncthreads();
    if (tid < 4) {
      int tot = 0;
      for (int k = 0; k < 64; ++k) tot += qsum[tid * 64 + k];
      qsum[256 + tid] = tot;
    }
    __syncthreads();
  }
  const int nb0 = ((qsum[256] + 255) & ~255) >> 7;
  const int nb1 = ((qsum[257] + 255) & ~255) >> 7;
  const int nb2 = ((qsum[258] + 255) & ~255) >> 7;
  const int nb3 = ((qsum[259] + 255) & ~255) >> 7;
  const int L = nb0 + nb1 + nb2 + nb3;
  if (id < L * 8) {
    int xl = id >> 3, y = id & 7, b = 0;
    if (xl >= nb0) { xl -= nb0; b = 1;
      if (xl >= nb1) { xl -= nb1; b = 2;
        if (xl >= nb2) { xl -= nb2; b = 3; } } }
    kv_body(cb, wk, wv, bk, bv, kh, vt, b * 2048 + xl * 128, y * 128, sh);
  } else if (id < L * 8 + 128) {
    const int q = id - L * 8;
    q_body(xb, wq, bq, qh, (q & 15) * 128, (q >> 4) * 128, sh);
  }
}

// ---------------------------------------------------------------------------
// Output projection: out[2048,1024] fp32 = ah @ Wo^T + bo. 64x128 tile,
// grid (32, 8) = 256 blocks (one per CU), 4 waves each 64 rows x 32 cols.
// The ONLY kernel that touches d_out.
__global__ __launch_bounds__(256)
void gemm_o(const unsigned short* __restrict__ A,
            const unsigned short* __restrict__ W,
            const float* __restrict__ bo, float* __restrict__ out) {
  constexpr int K = 1024;
  __shared__ __align__(16) unsigned short As[64 * 64];   // 8 KB
  __shared__ __align__(16) unsigned short Bs[128 * 64];  // 16 KB

  const int tid = threadIdx.x;
  const int wave = tid >> 6, lane = tid & 63;
  const int l15 = lane & 15, quad = lane >> 4;
  const int bm = blockIdx.x * 64, bn = blockIdx.y * 128;

  f32x4 acc[4][2] = {};

  for (int k0 = 0; k0 < K; k0 += 64) {
    __syncthreads();
#pragma unroll
    for (int c = 0; c < 2; ++c) {
      int s = c * 256 + tid;
      int m = s >> 3, k8 = (s & 7) ^ (m & 7);
      llds16(A + (size_t)(bm + m) * K + k0 + k8 * 8, &As[s * 8]);
    }
#pragma unroll
    for (int c = 0; c < 4; ++c) {
      int s = c * 256 + tid;
      int m = s >> 3, k8 = (s & 7) ^ (m & 7);
      llds16(W + (size_t)(bn + m) * K + k0 + k8 * 8, &Bs[s * 8]);
    }
    __syncthreads();
#pragma unroll
    for (int ks = 0; ks < 2; ++ks) {
      const int k8 = ks * 4 + quad;
      u16x8 af[4], bf[2];
#pragma unroll
      for (int i = 0; i < 4; ++i) {
        int m = i * 16 + l15;
        af[i] = *(const u16x8*)(&As[(m * 8 + (k8 ^ (m & 7))) * 8]);
      }
#pragma unroll
      for (int i = 0; i < 2; ++i) {
        int n = wave * 32 + i * 16 + l15;
        bf[i] = *(const u16x8*)(&Bs[(n * 8 + (k8 ^ (n & 7))) * 8]);
      }
#pragma unroll
      for (int mi = 0; mi < 4; ++mi)
#pragma unroll
        for (int ni = 0; ni < 2; ++ni)
          acc[mi][ni] = mfma16(af[mi], bf[ni], acc[mi][ni]);
    }
  }

#pragma unroll
  for (int mi = 0; mi < 4; ++mi)
#pragma unroll
    for (int ni = 0; ni < 2; ++ni)
#pragma unroll
      for (int r = 0; r < 4; ++r) {
        int row = bm + mi * 16 + quad * 4 + r;
        int col = bn + wave * 32 + ni * 16 + l15;
        out[(size_t)row * 1024 + col] = acc[mi][ni][r] + bo[col];
      }
}

// ---------------------------------------------------------------------------
// Split-K flash attention over COMPACTED keys, fixed-max softmax.
// Grid (64 bh, 8 qblk), block 256. cnt recomputed from the mask in-block
// (wave shuffle-reduce, no cross-kernel state). Wave w covers keys
// {w*64 + 256t}, t < T = ceil(cnt/256). Bias register-computed: uniform -8
// for full tiles, per-element (-8 / -1e30) when the stripe straddles cnt
// (pad K/V rows come from zero-filled ctx rows -> finite). No barriers in
// the main loop. Q/K/V FRAGMENT-MAJOR (contiguous 1KB wave-loads).
// launch_bounds(256,2): VGPR cap 256 (audit ~210) -> 2 blocks/CU resident.
// PS: p_lds row stride in u16. MUST be == 0 mod 8 (16 B) -- P fragments are
// read as u16x8 (ds_read_b128); any other stride misaligns odd q-rows.
#define PS 72
__global__ __launch_bounds__(256, 2)
void attn_kernel(const unsigned short* __restrict__ Q,   // frag-major [64][32][8][16][8]
                 const unsigned short* __restrict__ K,   // frag-major [64][128][8][16][8]
                 const unsigned short* __restrict__ Vt,  // frag-major [64][32][4][8][16][8]
                 const int* __restrict__ mask,           // [4][2048]
                 unsigned short* __restrict__ O) {       // [4][512][1024]
  __shared__ __align__(16) unsigned short p_lds[4][2][16 * PS];
  __shared__ float l_lds[4][64];
  __shared__ __align__(16) float o_comb[64][68];
  __shared__ int wsum[4];

  const int tid = threadIdx.x;
  const int wave = tid >> 6, lane = tid & 63;
  const int l15 = lane & 15, quad = lane >> 4;
  const int bh = blockIdx.x, b = bh >> 4, h = bh & 15;
  const int q0 = blockIdx.y * 64;

  {  // valid-key count for this batch (2048 ints, L2-hit)
    const int* mb = mask + b * 2048;
    int s = 0;
#pragma unroll
    for (int j = 0; j < 8; ++j) s += (mb[tid * 8 + j] != 0);
#pragma unroll
    for (int off = 1; off < 64; off <<= 1) s += __shfl_xor(s, off, 64);
    if (lane == 0) wsum[wave] = s;
    __syncthreads();
  }
  const int c = wsum[0] + wsum[1] + wsum[2] + wsum[3];
  const int T = (c + 255) >> 8;  // number of 256-key macro tiles

  const unsigned short* Qb = Q + (size_t)bh * 32768 + (size_t)(q0 >> 4) * 1024;
  const unsigned short* Kb = K + (size_t)bh * 131072;
  const unsigned short* Vb = Vt + (size_t)bh * 131072;

  // Q fragments (frag-major): one contiguous 1KB wave-load each.
  u16x8 aq[4][2];
#pragma unroll
  for (int qg = 0; qg < 4; ++qg)
#pragma unroll
    for (int ks = 0; ks < 2; ++ks)
      aq[qg][ks] = *(const u16x8*)(Qb + ((qg * 8 + ks * 4 + quad) * 16 + l15) * 8);

  f32x4 o_acc[4][4] = {};
  float l_s[4] = {0.f, 0.f, 0.f, 0.f};

  u16x8 kf[2][4];

  auto load_k = [&](int kb) {
    const int kg0 = kb >> 4;
#pragma unroll
    for (int ns = 0; ns < 4; ++ns)
#pragma unroll
      for (int ks = 0; ks < 2; ++ks)
        kf[ks][ns] = *(const u16x8*)(Kb + (((size_t)(kg0 + ns) * 8 + ks * 4 + quad) * 16 + l15) * 8);
  };

  load_k(wave * 64);

#pragma unroll 1
  for (int t = 0; t < T; ++t) {
    const int kb = wave * 64 + t * 256;
    const int kb_next = kb + (t + 1 < T ? 256 : 0);

    // V^T frags (frag-major, contiguous): consumed in PV, well after issue.
    u16x8 vf[2][4];
    const int kt4 = (kb >> 6) * 4;
#pragma unroll
    for (int nd = 0; nd < 4; ++nd)
#pragma unroll
      for (int ks = 0; ks < 2; ++ks)
        vf[ks][nd] = *(const u16x8*)(Vb + (((size_t)(kt4 + nd) * 8 + ks * 4 + quad) * 16 + l15) * 8);

    // register bias: uniform -8 unless this 64-key stripe straddles cnt
    f32x4 bfr[4];
    if (kb + 64 <= c) {
#pragma unroll
      for (int ns = 0; ns < 4; ++ns)
        bfr[ns] = f32x4{-8.f, -8.f, -8.f, -8.f};
    } else {
#pragma unroll
      for (int ns = 0; ns < 4; ++ns)
#pragma unroll
        for (int r = 0; r < 4; ++r)
          bfr[ns][r] = (kb + ns * 16 + quad * 4 + r < c) ? -8.f : -1e30f;
    }

#pragma unroll
    for (int qg = 0; qg < 4; ++qg) {
      // S^T tile: D[key = ns*16+quad*4+r][q = l15], C-init = bias (-8 shift)
      f32x4 sfr[4];
#pragma unroll
      for (int ns = 0; ns < 4; ++ns) {
        f32x4 sa = bfr[ns];
#pragma unroll
        for (int ks = 0; ks < 2; ++ks)
          sa = mfma16(kf[ks][ns], aq[qg][ks], sa);
        sfr[ns] = sa;
      }

      // kf dead after qg==3's S: reload for next tile now (covered by the
      // remaining softmax + PV of this qg).
      if (qg == 3) load_k(kb_next);

      float rsum = 0.f;
#pragma unroll
      for (int ns = 0; ns < 4; ++ns) {
        unsigned int pr[4];
#pragma unroll
        for (int r = 0; r < 4; ++r) {
          float p = exp2_fast(sfr[ns][r]);
          unsigned int u = __builtin_bit_cast(unsigned int, p) & 0xffff0000u;
          rsum += __builtin_bit_cast(float, u);  // sum TRUNCATED p: consistent with PV
          pr[r] = u;
        }
        uint2 pw;
        pw.x = __builtin_amdgcn_perm(pr[1], pr[0], 0x07060302u);
        pw.y = __builtin_amdgcn_perm(pr[3], pr[2], 0x07060302u);
        *(uint2*)&p_lds[wave][qg & 1][l15 * PS + ns * 16 + quad * 4] = pw;
      }
      rsum += __shfl_xor(rsum, 16, 64);
      rsum += __shfl_xor(rsum, 32, 64);
      l_s[qg] += rsum;

      // PV: A = P (lane=q, elems=key) from p_lds; B = V^T frags
#pragma unroll
      for (int ks = 0; ks < 2; ++ks) {
        u16x8 pf = *(const u16x8*)&p_lds[wave][qg & 1][l15 * PS + ks * 32 + quad * 8];
#pragma unroll
        for (int nd = 0; nd < 4; ++nd)
          o_acc[qg][nd] = mfma16(pf, vf[ks][nd], o_acc[qg][nd]);
      }
    }
  }

  // ---- combine the 4 waves' partial (l, o): plain sums (fixed max) ----
  if (quad == 0) {
#pragma unroll
    for (int qg = 0; qg < 4; ++qg)
      l_lds[wave][qg * 16 + l15] = l_s[qg];
  }
  __syncthreads();

  for (int w = 0; w < 4; ++w) {
    if (wave == w) {
#pragma unroll
      for (int qg = 0; qg < 4; ++qg)
#pragma unroll
        for (int r = 0; r < 4; ++r) {
          const int q = qg * 16 + quad * 4 + r;
#pragma unroll
          for (int nd = 0; nd < 4; ++nd) {
            const int d = nd * 16 + l15;
            float v = o_acc[qg][nd][r];
            if (w == 0) o_comb[q][d] = v;
            else        o_comb[q][d] += v;
          }
        }
    }
    __syncthreads();
  }

  // ---- final normalize + store (two u16x8 per thread) ----
  {
    const int q = tid >> 2, dc = (tid & 3) * 16;
    const float inv = 1.f / (l_lds[0][q] + l_lds[1][q] + l_lds[2][q] + l_lds[3][q]);
    unsigned short* Ob = O + ((size_t)(b * 512 + q0 + q)) * 1024 + h * 64 + dc;
    u16x8 o1, o2;
#pragma unroll
    for (int j = 0; j < 8; ++j) o1[j] = f2bf(o_comb[q][dc + j] * inv);
#pragma unroll
    for (int j = 0; j < 8; ++j) o2[j] = f2bf(o_comb[q][dc + 8 + j] * inv);
    *(u16x8*)(Ob) = o1;
    *(u16x8*)(Ob + 8) = o2;
  }
}

// ---------------------------------------------------------------------------
extern "C" void kernel_launch(void* const* d_in, const int* in_sizes, int n_in,
                              void* d_out, int out_size, void* d_ws, size_t ws_size,
                              hipStream_t stream) {
  const float* x   = (const float*)d_in[0];
  const float* ctx = (const float*)d_in[1];
  const int* mask  = (const int*)d_in[2];
  const float* Wq  = (const float*)d_in[3];
  const float* bq  = (const float*)d_in[4];
  const float* Wk  = (const float*)d_in[5];
  const float* bk  = (const float*)d_in[6];
  const float* Wv  = (const float*)d_in[7];
  const float* bv  = (const float*)d_in[8];
  const float* Wo  = (const float*)d_in[9];
  const float* bo  = (const float*)d_in[10];

  char* ws = (char*)d_ws;
  // [MB] xb 0-4, cb 4-20, w 20-28, qh 28-32, kh 32-48, vt 48-64, ah 64-68.
  // d_out is written ONLY by gemm_o (no scratch in the output buffer).
  unsigned short* xb  = (unsigned short*)(ws + ((size_t)0  << 20));
  unsigned short* cb  = (unsigned short*)(ws + ((size_t)4  << 20));
  unsigned short* wqb = (unsigned short*)(ws + ((size_t)20 << 20));
  unsigned short* wkb = (unsigned short*)(ws + ((size_t)22 << 20));
  unsigned short* wvb = (unsigned short*)(ws + ((size_t)24 << 20));
  unsigned short* wob = (unsigned short*)(ws + ((size_t)26 << 20));
  unsigned short* qh  = (unsigned short*)(ws + ((size_t)28 << 20));
  unsigned short* kh  = (unsigned short*)(ws + ((size_t)32 << 20));
  unsigned short* vt  = (unsigned short*)(ws + ((size_t)48 << 20));
  unsigned short* ah  = (unsigned short*)(ws + ((size_t)64 << 20));

  cast_fused<<<14336, 256, 0, stream>>>(x, ctx, Wq, Wk, Wv, Wo, mask,
                                        xb, cb, wqb, wkb, wvb, wob);
  gemm_qkv<<<640, 256, 0, stream>>>(xb, cb, wqb, wkb, wvb,
                                    bq, bk, bv, mask, qh, kh, vt);
  attn_kernel<<<dim3(64, 8), 256, 0, stream>>>(qh, kh, vt, mask, ah);
  gemm_o<<<dim3(32, 8), 256, 0, stream>>>(ah, wob, bo, (float*)d_out);
}